// Round 14
// baseline (118.207 us; speedup 1.0000x reference)
//
#include <hip/hip_runtime.h>
#include <math.h>

// critic_attention, round 14: r12 structure + depth-2 input prefetch.
// Evidence (r11-r13): per-wave issue ~6k cyc vs ~25k lifetime -> stall-bound;
// biggest identified exposed latency = phase-A obs loads (depth-1 prefetch
// covers ~350 of ~900 cyc HBM). Fix: TWO input slots; each slot's refill is
// issued 2 agent-computes before use (right after its cvt8). Static slot
// names (no runtime indexing - rule #20), shared transient acc -> only +16
// VGPR vs r12 (r9's unroll balloon avoided).
// Everything else identical to r12 (best @88.0us): 2-wave block, agent-split
// phase A, no-max softmax, LDS merge, col-split phase B, ws-packed weights.
//
// Fragment conventions (m89-verified, validated rounds 6-13):
//   A-frag: lane holds row (l&15), k = (l>>4)*8 + e
//   B-frag: lane holds col (l&15), k = (l>>4)*8 + e
//   D:      lane holds col (l&15) = channel, row = (l>>4)*4 + reg = item
//
// ws layout (halfs): W0h@0[2][4][4][16][8] W0l@4096 | W2h@8192[4][8][4][16][8]
//   W2l@24576 | W3h@40960 W3l@57344.  Total 73728 halfs = 147456 B.

#define SLOPE 0.01f
#define LOG2E 1.4426950408889634f

typedef _Float16 f16x8 __attribute__((ext_vector_type(8)));
typedef float f32x4 __attribute__((ext_vector_type(4)));

#define MFMA(a, b, c) __builtin_amdgcn_mfma_f32_16x16x32_f16((a), (b), (c), 0, 0, 0)

__device__ __forceinline__ float lrelu(float x) { return fmaxf(x, SLOPE * x); }

__device__ __forceinline__ float fast_tanh(float x) {
    float e = exp2f(x * (2.0f * LOG2E));
    float r = __fdividef(1.0f, e + 1.0f);
    return fmaf(-2.0f, r, 1.0f);
}

__device__ __forceinline__ f16x8 cvt8(const float f[8]) {
    f16x8 r;
#pragma unroll
    for (int e = 0; e < 8; ++e) r[e] = (_Float16)f[e];
    return r;
}

__device__ __forceinline__ void split8(const float f[8], f16x8& hi, f16x8& lo) {
#pragma unroll
    for (int e = 0; e < 8; ++e) {
        _Float16 h = (_Float16)f[e];
        hi[e] = h;
        lo[e] = (_Float16)(f[e] - (float)h);
    }
}

// ---------------- prep: split weights into per-lane fp16 hi/lo fragments ----------------
__global__ __launch_bounds__(256) void pack_weights(
    const float* __restrict__ W0, const float* __restrict__ W2,
    const float* __restrict__ W3, _Float16* __restrict__ ws)
{
    const int g = blockIdx.x * 256 + threadIdx.x;   // fragment group id
    if (g >= 4608) return;

    const float* src;
    int ks, ct, lg, lr, ncol, kmax;
    long hoff, loff;
    if (g < 512) {                       // W0: [2][4][4][16]
        ks = g >> 8; ct = (g >> 6) & 3; lg = (g >> 4) & 3; lr = g & 15;
        src = W0; ncol = 64; kmax = 40;
        hoff = (long)g * 8;  loff = hoff + 4096;
    } else if (g < 2560) {               // W2: [4][8][4][16]
        int gg = g - 512;
        ks = gg >> 9; ct = (gg >> 6) & 7; lg = (gg >> 4) & 3; lr = gg & 15;
        src = W2; ncol = 128; kmax = 128;
        hoff = 8192 + (long)gg * 8; loff = hoff + 16384;
    } else {                             // W3: [4][8][4][16]
        int gg = g - 2560;
        ks = gg >> 9; ct = (gg >> 6) & 7; lg = (gg >> 4) & 3; lr = gg & 15;
        src = W3; ncol = 128; kmax = 128;
        hoff = 40960 + (long)gg * 8; loff = hoff + 16384;
    }

    f16x8 hi, lo;
#pragma unroll
    for (int e = 0; e < 8; ++e) {
        const int k = ks * 32 + lg * 8 + e;
        const float v = (k < kmax) ? src[(long)k * ncol + ct * 16 + lr] : 0.f;
        _Float16 h = (_Float16)v;
        hi[e] = h;
        lo[e] = (_Float16)(v - (float)h);
    }
    *reinterpret_cast<f16x8*>(ws + hoff) = hi;
    *reinterpret_cast<f16x8*>(ws + loff) = lo;
}

// one "other" agent: consume slot (sq0,sq1,sc0,sc1); if pref_a >= 0, refill the
// SAME slot with agent pref_a right after the cvt (2-compute load coverage).
__device__ __forceinline__ void agent_other(
    float4& sq0, float4& sq1, float4& sc0, float4& sc1,
    const float* __restrict__ obase, const float* __restrict__ abase,
    int pref_a, int lg,
    const f16x8 (&w0h)[2][4], const f16x8 (&w0l)[2][4],
    const float (&b0c)[4], const float (&W1oc)[4],
    const float (&a_self)[4], float (&s)[4], float (&xsum)[4][4])
{
    float b0f[8] = {sq0.x, sq0.y, sq0.z, sq0.w, sq1.x, sq1.y, sq1.z, sq1.w};
    float b1f[8] = {sc0.x, sc0.y, sc0.z, sc0.w, sc1.x, sc1.y, sc1.z, sc1.w};
    f16x8 bi0 = cvt8(b0f);
    f16x8 bi1 = cvt8(b1f);

    if (pref_a >= 0) {   // refill this slot, consumed 2 computes from now
        sq0 = *reinterpret_cast<const float4*>(obase + pref_a * 32);
        sq1 = *reinterpret_cast<const float4*>(obase + pref_a * 32 + 4);
        if (lg == 0) {
            sc0 = *reinterpret_cast<const float4*>(abase + pref_a * 8);
            sc1 = *reinterpret_cast<const float4*>(abase + pref_a * 8 + 4);
        }
    }

    f32x4 acc[4];
#pragma unroll
    for (int ct = 0; ct < 4; ++ct) {
        acc[ct] = (f32x4){b0c[ct], b0c[ct], b0c[ct], b0c[ct]};  // bias folded
        acc[ct] = MFMA(bi0, w0l[0][ct], acc[ct]);
        acc[ct] = MFMA(bi0, w0h[0][ct], acc[ct]);
        acc[ct] = MFMA(bi1, w0l[1][ct], acc[ct]);
        acc[ct] = MFMA(bi1, w0h[1][ct], acc[ct]);
    }

    float xa[4][4], p[4];
#pragma unroll
    for (int j = 0; j < 4; ++j) {
#pragma unroll
        for (int ct = 0; ct < 4; ++ct)
            xa[ct][j] = fast_tanh(acc[ct][j]);
        p[j] = xa[0][j] * W1oc[0];
        p[j] = fmaf(xa[1][j], W1oc[1], p[j]);
        p[j] = fmaf(xa[2][j], W1oc[2], p[j]);
        p[j] = fmaf(xa[3][j], W1oc[3], p[j]);
        p[j] += __shfl_xor(p[j], 1, 64);
        p[j] += __shfl_xor(p[j], 2, 64);
        p[j] += __shfl_xor(p[j], 4, 64);
        p[j] += __shfl_xor(p[j], 8, 64);
    }
    // bounded logits -> softmax without max-subtraction, pure accumulation
#pragma unroll
    for (int j = 0; j < 4; ++j) {
        const float e = exp2f(lrelu(a_self[j] + p[j]) * LOG2E);
        s[j] += e;
#pragma unroll
        for (int ct = 0; ct < 4; ++ct)
            xsum[ct][j] = fmaf(e, xa[ct][j], xsum[ct][j]);
    }
}

__global__ __launch_bounds__(128, 2) void critic_attention_kernel(
    const float* __restrict__ obs, const float* __restrict__ act,
    const float* __restrict__ b0, const float* __restrict__ W1,
    const float* __restrict__ b1v, const float* __restrict__ b2,
    const float* __restrict__ b3, const float* __restrict__ Wc,
    const float* __restrict__ bcv, const _Float16* __restrict__ ws,
    float* __restrict__ out)
{
    __shared__ float xcat[16 * 132];   // x_cat / x1, 16 items; stride 132 = 16B-aligned
    __shared__ float part[16 * 68];    // wave1 partial xsum
    __shared__ float ps[16];           // wave1 partial s
    __shared__ float vpart[32];        // Wc partials per wave

    const int t = threadIdx.x;
    const int lane = t & 63;
    const int w = t >> 6;              // wave 0/1
    const int lr = lane & 15;          // A-row (item) / D-col (channel)
    const int lg = lane >> 4;          // k-chunk / D-row-group

    const long ibase = (long)blockIdx.x * 16;

    // W0 fragments (resident through the agent loop)
    f16x8 w0h[2][4], w0l[2][4];
#pragma unroll
    for (int ks = 0; ks < 2; ++ks)
#pragma unroll
        for (int ct = 0; ct < 4; ++ct) {
            const long o = (((long)(ks * 4 + ct) * 4 + lg) * 16 + lr) * 8;
            w0h[ks][ct] = *reinterpret_cast<const f16x8*>(ws + o);
            w0l[ks][ct] = *reinterpret_cast<const f16x8*>(ws + 4096 + o);
        }

    float b0c[4], W1sc[4], W1oc[4];
#pragma unroll
    for (int ct = 0; ct < 4; ++ct) {
        b0c[ct]  = b0[ct * 16 + lr];
        W1sc[ct] = W1[ct * 16 + lr];
        W1oc[ct] = W1[64 + ct * 16 + lr];
    }
    const float b1s = b1v[0];

    const float* obase = obs + (ibase + lr) * 512 + lg * 8;   // this lane's item row
    const float* abase = act + (ibase + lr) * 128;            // lg==0 lanes only

    const int fb = w ? 8 : 1;          // first "other" agent of this wave
    const int sb = w ? 9 : 2;          // second (peel's prefetch target)

    // preload slot A <- agent 0, slot B <- first other
    float4 Aq0 = *reinterpret_cast<const float4*>(obase);
    float4 Aq1 = *reinterpret_cast<const float4*>(obase + 4);
    float4 Bq0 = *reinterpret_cast<const float4*>(obase + fb * 32);
    float4 Bq1 = *reinterpret_cast<const float4*>(obase + fb * 32 + 4);
    float4 Ac0 = make_float4(0.f, 0.f, 0.f, 0.f), Ac1 = Ac0;
    float4 Bc0 = Ac0, Bc1 = Ac0;
    if (lg == 0) {
        Ac0 = *reinterpret_cast<const float4*>(abase);
        Ac1 = *reinterpret_cast<const float4*>(abase + 4);
        Bc0 = *reinterpret_cast<const float4*>(abase + fb * 8);
        Bc1 = *reinterpret_cast<const float4*>(abase + fb * 8 + 4);
    }

    // ---------------- agent 0 (slot A): both waves (wave1 only needs a_self) ----------------
    float a_self[4], s[4], xsum[4][4];
    {
        float b0f[8] = {Aq0.x, Aq0.y, Aq0.z, Aq0.w, Aq1.x, Aq1.y, Aq1.z, Aq1.w};
        float b1f[8] = {Ac0.x, Ac0.y, Ac0.z, Ac0.w, Ac1.x, Ac1.y, Ac1.z, Ac1.w};
        f16x8 bi0 = cvt8(b0f);
        f16x8 bi1 = cvt8(b1f);

        // refill slot A with this wave's second "other"
        Aq0 = *reinterpret_cast<const float4*>(obase + sb * 32);
        Aq1 = *reinterpret_cast<const float4*>(obase + sb * 32 + 4);
        if (lg == 0) {
            Ac0 = *reinterpret_cast<const float4*>(abase + sb * 8);
            Ac1 = *reinterpret_cast<const float4*>(abase + sb * 8 + 4);
        }

        f32x4 acc[4];
#pragma unroll
        for (int ct = 0; ct < 4; ++ct) {
            acc[ct] = (f32x4){b0c[ct], b0c[ct], b0c[ct], b0c[ct]};  // bias folded
            acc[ct] = MFMA(bi0, w0l[0][ct], acc[ct]);
            acc[ct] = MFMA(bi0, w0h[0][ct], acc[ct]);
            acc[ct] = MFMA(bi1, w0l[1][ct], acc[ct]);
            acc[ct] = MFMA(bi1, w0h[1][ct], acc[ct]);
        }

        float xa[4][4], p[4];
#pragma unroll
        for (int j = 0; j < 4; ++j) {
#pragma unroll
            for (int ct = 0; ct < 4; ++ct)
                xa[ct][j] = lrelu(acc[ct][j]);
            p[j] = xa[0][j] * W1sc[0];
            p[j] = fmaf(xa[1][j], W1sc[1], p[j]);
            p[j] = fmaf(xa[2][j], W1sc[2], p[j]);
            p[j] = fmaf(xa[3][j], W1sc[3], p[j]);
            p[j] += __shfl_xor(p[j], 1, 64);
            p[j] += __shfl_xor(p[j], 2, 64);
            p[j] += __shfl_xor(p[j], 4, 64);
            p[j] += __shfl_xor(p[j], 8, 64);
            a_self[j] = b1s + p[j];
            s[j] = 0.f;
#pragma unroll
            for (int ct = 0; ct < 4; ++ct) xsum[ct][j] = 0.f;
        }
        if (w == 0) {
#pragma unroll
            for (int ct = 0; ct < 4; ++ct)
#pragma unroll
                for (int j = 0; j < 4; ++j)
                    xcat[(lg * 4 + j) * 132 + ct * 16 + lr] = xa[ct][j];   // x_self
        }
    }

    // ---------------- "other" agents, alternating slots, 2-deep prefetch ----------------
#define OTHER(S, P) agent_other(S##q0, S##q1, S##c0, S##c1, obase, abase, (P), lg, \
                                w0h, w0l, b0c, W1oc, a_self, s, xsum)
    if (w == 0) {
        // agents: B=1(pre 3), A=2(pre 4), B=3(pre 5), A=4(pre 6), B=5(pre 7), A=6, B=7
        OTHER(B, 3); OTHER(A, 4); OTHER(B, 5); OTHER(A, 6);
        OTHER(B, 7); OTHER(A, -1); OTHER(B, -1);
    } else {
        // agents: B=8(pre 10), A=9(pre 11), ..., A=13(pre 15), B=14, A=15
        OTHER(B, 10); OTHER(A, 11); OTHER(B, 12); OTHER(A, 13);
        OTHER(B, 14); OTHER(A, 15); OTHER(B, -1); OTHER(A, -1);
    }
#undef OTHER

    // ---------------- merge wave1 partials into wave0, write x_sum ----------------
    if (w == 1) {
#pragma unroll
        for (int j = 0; j < 4; ++j) {
#pragma unroll
            for (int ct = 0; ct < 4; ++ct)
                part[(lg * 4 + j) * 68 + ct * 16 + lr] = xsum[ct][j];
            if (lr == 0) ps[lg * 4 + j] = s[j];
        }
    }
    __syncthreads();
    if (w == 0) {
#pragma unroll
        for (int j = 0; j < 4; ++j) {
            const float stot = s[j] + ps[lg * 4 + j];
            const float inv = __fdividef(1.f, stot);
#pragma unroll
            for (int ct = 0; ct < 4; ++ct)
                xcat[(lg * 4 + j) * 132 + 64 + ct * 16 + lr] =
                    (xsum[ct][j] + part[(lg * 4 + j) * 68 + ct * 16 + lr]) * inv;
        }
    }
    __syncthreads();

    // ---------------- phase B: wave w owns cols [w*64, w*64+64) ----------------
    float b2c[4], b3c[4], Wcc[4];
#pragma unroll
    for (int ct = 0; ct < 4; ++ct) {
        const int ctg = w * 4 + ct;
        b2c[ct] = b2[ctg * 16 + lr];
        b3c[ct] = b3[ctg * 16 + lr];
        Wcc[ct] = Wc[ctg * 16 + lr];
    }
    const float bcs = bcv[0];

    f32x4 acc2[4];
#pragma unroll
    for (int ct = 0; ct < 4; ++ct)
        acc2[ct] = (f32x4){b2c[ct], b2c[ct], b2c[ct], b2c[ct]};   // bias folded
#pragma unroll
    for (int ks = 0; ks < 4; ++ks) {
        const float* xr = xcat + lr * 132 + ks * 32 + lg * 8;
        float4 r0 = *reinterpret_cast<const float4*>(xr);
        float4 r1 = *reinterpret_cast<const float4*>(xr + 4);
        float av[8] = {r0.x, r0.y, r0.z, r0.w, r1.x, r1.y, r1.z, r1.w};
        f16x8 ah, al;
        split8(av, ah, al);
#pragma unroll
        for (int ct = 0; ct < 4; ++ct) {
            const int ctg = w * 4 + ct;
            const long gg = ((long)(ks * 8 + ctg) * 4 + lg) * 16 + lr;
            f16x8 bh = *reinterpret_cast<const f16x8*>(ws + 8192 + gg * 8);
            f16x8 bl = *reinterpret_cast<const f16x8*>(ws + 24576 + gg * 8);
            acc2[ct] = MFMA(al, bh, acc2[ct]);
            acc2[ct] = MFMA(ah, bl, acc2[ct]);
            acc2[ct] = MFMA(ah, bh, acc2[ct]);
        }
    }
    __syncthreads();   // all x_cat reads done before x1 overwrite
#pragma unroll
    for (int ct = 0; ct < 4; ++ct)
#pragma unroll
        for (int j = 0; j < 4; ++j)
            xcat[(lg * 4 + j) * 132 + (w * 4 + ct) * 16 + lr] = lrelu(acc2[ct][j]);
    __syncthreads();

#pragma unroll
    for (int ct = 0; ct < 4; ++ct)
        acc2[ct] = (f32x4){b3c[ct], b3c[ct], b3c[ct], b3c[ct]};   // bias folded
#pragma unroll
    for (int ks = 0; ks < 4; ++ks) {
        const float* xr = xcat + lr * 132 + ks * 32 + lg * 8;
        float4 r0 = *reinterpret_cast<const float4*>(xr);
        float4 r1 = *reinterpret_cast<const float4*>(xr + 4);
        float av[8] = {r0.x, r0.y, r0.z, r0.w, r1.x, r1.y, r1.z, r1.w};
        f16x8 ah, al;
        split8(av, ah, al);
#pragma unroll
        for (int ct = 0; ct < 4; ++ct) {
            const int ctg = w * 4 + ct;
            const long gg = ((long)(ks * 8 + ctg) * 4 + lg) * 16 + lr;
            f16x8 bh = *reinterpret_cast<const f16x8*>(ws + 40960 + gg * 8);
            f16x8 bl = *reinterpret_cast<const f16x8*>(ws + 57344 + gg * 8);
            acc2[ct] = MFMA(al, bh, acc2[ct]);
            acc2[ct] = MFMA(ah, bl, acc2[ct]);
            acc2[ct] = MFMA(ah, bh, acc2[ct]);
        }
    }

    // value: per-lane partials over this wave's 64 cols, butterfly over lr
    float v[4];
#pragma unroll
    for (int j = 0; j < 4; ++j) {
        v[j] = lrelu(acc2[0][j]) * Wcc[0];
#pragma unroll
        for (int ct = 1; ct < 4; ++ct)
            v[j] = fmaf(lrelu(acc2[ct][j]), Wcc[ct], v[j]);
        v[j] += __shfl_xor(v[j], 1, 64);
        v[j] += __shfl_xor(v[j], 2, 64);
        v[j] += __shfl_xor(v[j], 4, 64);
        v[j] += __shfl_xor(v[j], 8, 64);
    }
    if (lr == 0) {
#pragma unroll
        for (int j = 0; j < 4; ++j)
            vpart[w * 16 + lg * 4 + j] = v[j];
    }
    __syncthreads();
    if (w == 0 && lr == 0) {
#pragma unroll
        for (int j = 0; j < 4; ++j) {
            const int row = lg * 4 + j;
            out[ibase + row] = vpart[row] + vpart[16 + row] + bcs;
        }
    }
}

extern "C" void kernel_launch(void* const* d_in, const int* in_sizes, int n_in,
                              void* d_out, int out_size, void* d_ws, size_t ws_size,
                              hipStream_t stream) {
    (void)in_sizes; (void)n_in; (void)ws_size; (void)out_size;
    const float* obs = (const float*)d_in[0];
    const float* act = (const float*)d_in[1];
    const float* W0  = (const float*)d_in[2];
    const float* b0  = (const float*)d_in[3];
    const float* W1  = (const float*)d_in[4];
    const float* b1  = (const float*)d_in[5];
    const float* W2  = (const float*)d_in[6];
    const float* b2  = (const float*)d_in[7];
    const float* W3  = (const float*)d_in[8];
    const float* b3  = (const float*)d_in[9];
    const float* Wc  = (const float*)d_in[10];
    const float* bc  = (const float*)d_in[11];
    _Float16* ws = (_Float16*)d_ws;

    pack_weights<<<dim3(18), dim3(256), 0, stream>>>(W0, W2, W3, ws);
    critic_attention_kernel<<<dim3(65536 / 16), dim3(128), 0, stream>>>(
        obs, act, b0, W1, b1, b2, b3, Wc, bc, ws, (float*)d_out);
}

// Round 15
// 100.505 us; speedup vs baseline: 1.1761x; 1.1761x over previous
//
#include <hip/hip_runtime.h>
#include <math.h>

// critic_attention, round 15: r12 skeleton + paired phase-A agents.
// r14 post-mortem: VGPR=128 + WRITE 30MB = spill cliff. This round buys
// register headroom by dropping the phase-A W0 lo-half (hi-fp16 weights only:
// -16 VGPR, -8 MFMA/agent; predicted absmax ~7e-4..1.2e-3 < 1.875e-3 from the
// r8->r9 calibration), then spends it on a PAIRED agent loop: both agents'
// MFMAs issue together, both finish chains (tanh/dot/shfl/exp) are adjacent
// so the compiler cross-schedules them - agent F's 4-deep ds_bpermute wait
// hides under agent S's 16 tanh and vice versa. 2-deep slot refills (loads
// issued one full pair-body ~800cyc ahead). Rolled loop (runtime bounds),
// static register arrays only (rule #20).
// Phase B unchanged from r12 (full hi/lo split precision).
//
// Fragment conventions (m89-verified, validated rounds 6-14):
//   A-frag: lane holds row (l&15)=item, k=(l>>4)*8+e
//   B-frag: lane holds col (l&15)=channel-sub, k=(l>>4)*8+e
//   D:      lane holds col (l&15), row=(l>>4)*4+reg = item
//
// ws layout (halfs): W0h@0[2][4][4][16][8] W0l@4096 (unused in kernel now) |
//   W2h@8192[4][8][4][16][8] W2l@24576 | W3h@40960 W3l@57344.

#define SLOPE 0.01f
#define LOG2E 1.4426950408889634f

typedef _Float16 f16x8 __attribute__((ext_vector_type(8)));
typedef float f32x4 __attribute__((ext_vector_type(4)));

#define MFMA(a, b, c) __builtin_amdgcn_mfma_f32_16x16x32_f16((a), (b), (c), 0, 0, 0)

__device__ __forceinline__ float lrelu(float x) { return fmaxf(x, SLOPE * x); }

__device__ __forceinline__ float fast_tanh(float x) {
    float e = exp2f(x * (2.0f * LOG2E));
    float r = __fdividef(1.0f, e + 1.0f);
    return fmaf(-2.0f, r, 1.0f);
}

__device__ __forceinline__ f16x8 cvt8(const float f[8]) {
    f16x8 r;
#pragma unroll
    for (int e = 0; e < 8; ++e) r[e] = (_Float16)f[e];
    return r;
}

__device__ __forceinline__ void split8(const float f[8], f16x8& hi, f16x8& lo) {
#pragma unroll
    for (int e = 0; e < 8; ++e) {
        _Float16 h = (_Float16)f[e];
        hi[e] = h;
        lo[e] = (_Float16)(f[e] - (float)h);
    }
}

// ---------------- prep: split weights into per-lane fp16 hi/lo fragments ----------------
__global__ __launch_bounds__(256) void pack_weights(
    const float* __restrict__ W0, const float* __restrict__ W2,
    const float* __restrict__ W3, _Float16* __restrict__ ws)
{
    const int g = blockIdx.x * 256 + threadIdx.x;   // fragment group id
    if (g >= 4608) return;

    const float* src;
    int ks, ct, lg, lr, ncol, kmax;
    long hoff, loff;
    if (g < 512) {                       // W0: [2][4][4][16]
        ks = g >> 8; ct = (g >> 6) & 3; lg = (g >> 4) & 3; lr = g & 15;
        src = W0; ncol = 64; kmax = 40;
        hoff = (long)g * 8;  loff = hoff + 4096;
    } else if (g < 2560) {               // W2: [4][8][4][16]
        int gg = g - 512;
        ks = gg >> 9; ct = (gg >> 6) & 7; lg = (gg >> 4) & 3; lr = gg & 15;
        src = W2; ncol = 128; kmax = 128;
        hoff = 8192 + (long)gg * 8; loff = hoff + 16384;
    } else {                             // W3: [4][8][4][16]
        int gg = g - 2560;
        ks = gg >> 9; ct = (gg >> 6) & 7; lg = (gg >> 4) & 3; lr = gg & 15;
        src = W3; ncol = 128; kmax = 128;
        hoff = 40960 + (long)gg * 8; loff = hoff + 16384;
    }

    f16x8 hi, lo;
#pragma unroll
    for (int e = 0; e < 8; ++e) {
        const int k = ks * 32 + lg * 8 + e;
        const float v = (k < kmax) ? src[(long)k * ncol + ct * 16 + lr] : 0.f;
        _Float16 h = (_Float16)v;
        hi[e] = h;
        lo[e] = (_Float16)(v - (float)h);
    }
    *reinterpret_cast<f16x8*>(ws + hoff) = hi;
    *reinterpret_cast<f16x8*>(ws + loff) = lo;
}

__global__ __launch_bounds__(128, 2) void critic_attention_kernel(
    const float* __restrict__ obs, const float* __restrict__ act,
    const float* __restrict__ b0, const float* __restrict__ W1,
    const float* __restrict__ b1v, const float* __restrict__ b2,
    const float* __restrict__ b3, const float* __restrict__ Wc,
    const float* __restrict__ bcv, const _Float16* __restrict__ ws,
    float* __restrict__ out)
{
    __shared__ float xcat[16 * 132];   // x_cat / x1, 16 items; stride 132 = 16B-aligned
    __shared__ float part[16 * 68];    // wave1 partial xsum
    __shared__ float ps[16];           // wave1 partial s
    __shared__ float vpart[32];        // Wc partials per wave

    const int t = threadIdx.x;
    const int lane = t & 63;
    const int w = t >> 6;              // wave 0/1
    const int lr = lane & 15;          // A-row (item) / D-col
    const int lg = lane >> 4;          // k-chunk / D-row-group

    const long ibase = (long)blockIdx.x * 16;

    // W0 HI fragments only (phase-A weights single-fp16; -16 VGPR, -8 MFMA/agent)
    f16x8 w0h[2][4];
#pragma unroll
    for (int ks = 0; ks < 2; ++ks)
#pragma unroll
        for (int ct = 0; ct < 4; ++ct) {
            const long o = (((long)(ks * 4 + ct) * 4 + lg) * 16 + lr) * 8;
            w0h[ks][ct] = *reinterpret_cast<const f16x8*>(ws + o);
        }

    float b0c[4], W1sc[4], W1oc[4];
#pragma unroll
    for (int ct = 0; ct < 4; ++ct) {
        b0c[ct]  = b0[ct * 16 + lr];
        W1sc[ct] = W1[ct * 16 + lr];
        W1oc[ct] = W1[64 + ct * 16 + lr];
    }
    const float b1s = b1v[0];

    const float* obase = obs + (ibase + lr) * 512 + lg * 8;   // this lane's item row
    const float* abase = act + (ibase + lr) * 128;            // lg==0 lanes only

    const int abeg = w ? 8 : 1;        // wave0: agents 1..7; wave1: agents 8..15
    const int aend = w ? 16 : 8;

    // two input slots: S (first of pair), F (second of pair)
    float4 Sq0, Sq1, Sc0, Sc1, Fq0, Fq1, Fc0, Fc1;
    // prologue: F <- agent 0, S <- first other
    Fq0 = *reinterpret_cast<const float4*>(obase);
    Fq1 = *reinterpret_cast<const float4*>(obase + 4);
    Sq0 = *reinterpret_cast<const float4*>(obase + abeg * 32);
    Sq1 = *reinterpret_cast<const float4*>(obase + abeg * 32 + 4);
    Fc0 = make_float4(0.f, 0.f, 0.f, 0.f); Fc1 = Fc0;
    Sc0 = Fc0; Sc1 = Fc0;
    if (lg == 0) {
        Fc0 = *reinterpret_cast<const float4*>(abase);
        Fc1 = *reinterpret_cast<const float4*>(abase + 4);
        Sc0 = *reinterpret_cast<const float4*>(abase + abeg * 8);
        Sc1 = *reinterpret_cast<const float4*>(abase + abeg * 8 + 4);
    }

    // ---------------- agent 0 (slot F): both waves (wave1 only needs a_self) ----------------
    float a_self[4], s[4], xsum[4][4];
    {
        float f0[8] = {Fq0.x, Fq0.y, Fq0.z, Fq0.w, Fq1.x, Fq1.y, Fq1.z, Fq1.w};
        float f1[8] = {Fc0.x, Fc0.y, Fc0.z, Fc0.w, Fc1.x, Fc1.y, Fc1.z, Fc1.w};
        f16x8 bi0 = cvt8(f0);
        f16x8 bi1 = cvt8(f1);

        // refill F <- second other (abeg+1)
        Fq0 = *reinterpret_cast<const float4*>(obase + (abeg + 1) * 32);
        Fq1 = *reinterpret_cast<const float4*>(obase + (abeg + 1) * 32 + 4);
        if (lg == 0) {
            Fc0 = *reinterpret_cast<const float4*>(abase + (abeg + 1) * 8);
            Fc1 = *reinterpret_cast<const float4*>(abase + (abeg + 1) * 8 + 4);
        }

        f32x4 acc[4];
#pragma unroll
        for (int ct = 0; ct < 4; ++ct) {
            acc[ct] = (f32x4){b0c[ct], b0c[ct], b0c[ct], b0c[ct]};
            acc[ct] = MFMA(bi0, w0h[0][ct], acc[ct]);
            acc[ct] = MFMA(bi1, w0h[1][ct], acc[ct]);
        }

        float xa[4][4], p[4];
#pragma unroll
        for (int j = 0; j < 4; ++j) {
#pragma unroll
            for (int ct = 0; ct < 4; ++ct)
                xa[ct][j] = lrelu(acc[ct][j]);
            p[j] = xa[0][j] * W1sc[0];
            p[j] = fmaf(xa[1][j], W1sc[1], p[j]);
            p[j] = fmaf(xa[2][j], W1sc[2], p[j]);
            p[j] = fmaf(xa[3][j], W1sc[3], p[j]);
            p[j] += __shfl_xor(p[j], 1, 64);
            p[j] += __shfl_xor(p[j], 2, 64);
            p[j] += __shfl_xor(p[j], 4, 64);
            p[j] += __shfl_xor(p[j], 8, 64);
            a_self[j] = b1s + p[j];
            s[j] = 0.f;
#pragma unroll
            for (int ct = 0; ct < 4; ++ct) xsum[ct][j] = 0.f;
        }
        if (w == 0) {
#pragma unroll
            for (int ct = 0; ct < 4; ++ct)
#pragma unroll
                for (int j = 0; j < 4; ++j)
                    xcat[(lg * 4 + j) * 132 + ct * 16 + lr] = xa[ct][j];   // x_self
        }
    }

    // ---------------- paired "other" agents: a in S, a+1 in F ----------------
    for (int a = abeg; a + 1 < aend; a += 2) {
        float sf0[8] = {Sq0.x, Sq0.y, Sq0.z, Sq0.w, Sq1.x, Sq1.y, Sq1.z, Sq1.w};
        float sf1[8] = {Sc0.x, Sc0.y, Sc0.z, Sc0.w, Sc1.x, Sc1.y, Sc1.z, Sc1.w};
        float ff0[8] = {Fq0.x, Fq0.y, Fq0.z, Fq0.w, Fq1.x, Fq1.y, Fq1.z, Fq1.w};
        float ff1[8] = {Fc0.x, Fc0.y, Fc0.z, Fc0.w, Fc1.x, Fc1.y, Fc1.z, Fc1.w};
        f16x8 bS0 = cvt8(sf0), bS1 = cvt8(sf1);
        f16x8 bF0 = cvt8(ff0), bF1 = cvt8(ff1);

        // refill slots for the pair after next (full pair-body of latency cover)
        if (a + 2 < aend) {
            Sq0 = *reinterpret_cast<const float4*>(obase + (a + 2) * 32);
            Sq1 = *reinterpret_cast<const float4*>(obase + (a + 2) * 32 + 4);
            if (lg == 0) {
                Sc0 = *reinterpret_cast<const float4*>(abase + (a + 2) * 8);
                Sc1 = *reinterpret_cast<const float4*>(abase + (a + 2) * 8 + 4);
            }
        }
        if (a + 3 < aend) {
            Fq0 = *reinterpret_cast<const float4*>(obase + (a + 3) * 32);
            Fq1 = *reinterpret_cast<const float4*>(obase + (a + 3) * 32 + 4);
            if (lg == 0) {
                Fc0 = *reinterpret_cast<const float4*>(abase + (a + 3) * 8);
                Fc1 = *reinterpret_cast<const float4*>(abase + (a + 3) * 8 + 4);
            }
        }

        f32x4 accA[4], accB[4];
#pragma unroll
        for (int ct = 0; ct < 4; ++ct) {
            accA[ct] = (f32x4){b0c[ct], b0c[ct], b0c[ct], b0c[ct]};
            accA[ct] = MFMA(bS0, w0h[0][ct], accA[ct]);
            accA[ct] = MFMA(bS1, w0h[1][ct], accA[ct]);
            accB[ct] = (f32x4){b0c[ct], b0c[ct], b0c[ct], b0c[ct]};
            accB[ct] = MFMA(bF0, w0h[0][ct], accB[ct]);
            accB[ct] = MFMA(bF1, w0h[1][ct], accB[ct]);
        }

        // both finish chains adjacent -> compiler cross-schedules:
        // A's shfl waits hide under B's tanh block and vice versa
        float xaA[4][4], xaB[4][4], pA[4], pB[4];
#pragma unroll
        for (int j = 0; j < 4; ++j) {
#pragma unroll
            for (int ct = 0; ct < 4; ++ct)
                xaA[ct][j] = fast_tanh(accA[ct][j]);
            pA[j] = xaA[0][j] * W1oc[0];
            pA[j] = fmaf(xaA[1][j], W1oc[1], pA[j]);
            pA[j] = fmaf(xaA[2][j], W1oc[2], pA[j]);
            pA[j] = fmaf(xaA[3][j], W1oc[3], pA[j]);
        }
#pragma unroll
        for (int j = 0; j < 4; ++j) {
#pragma unroll
            for (int ct = 0; ct < 4; ++ct)
                xaB[ct][j] = fast_tanh(accB[ct][j]);
            pB[j] = xaB[0][j] * W1oc[0];
            pB[j] = fmaf(xaB[1][j], W1oc[1], pB[j]);
            pB[j] = fmaf(xaB[2][j], W1oc[2], pB[j]);
            pB[j] = fmaf(xaB[3][j], W1oc[3], pB[j]);
        }
#pragma unroll
        for (int j = 0; j < 4; ++j) {
            pA[j] += __shfl_xor(pA[j], 1, 64);
            pB[j] += __shfl_xor(pB[j], 1, 64);
            pA[j] += __shfl_xor(pA[j], 2, 64);
            pB[j] += __shfl_xor(pB[j], 2, 64);
            pA[j] += __shfl_xor(pA[j], 4, 64);
            pB[j] += __shfl_xor(pB[j], 4, 64);
            pA[j] += __shfl_xor(pA[j], 8, 64);
            pB[j] += __shfl_xor(pB[j], 8, 64);
        }
#pragma unroll
        for (int j = 0; j < 4; ++j) {
            const float eA = exp2f(lrelu(a_self[j] + pA[j]) * LOG2E);
            const float eB = exp2f(lrelu(a_self[j] + pB[j]) * LOG2E);
            s[j] += eA + eB;
#pragma unroll
            for (int ct = 0; ct < 4; ++ct) {
                xsum[ct][j] = fmaf(eA, xaA[ct][j], xsum[ct][j]);
                xsum[ct][j] = fmaf(eB, xaB[ct][j], xsum[ct][j]);
            }
        }
    }

    // tail (wave0 only: 7 others is odd; agent 7 sits in slot S)
    if ((aend - abeg) & 1) {
        float sf0[8] = {Sq0.x, Sq0.y, Sq0.z, Sq0.w, Sq1.x, Sq1.y, Sq1.z, Sq1.w};
        float sf1[8] = {Sc0.x, Sc0.y, Sc0.z, Sc0.w, Sc1.x, Sc1.y, Sc1.z, Sc1.w};
        f16x8 bS0 = cvt8(sf0), bS1 = cvt8(sf1);

        f32x4 acc[4];
#pragma unroll
        for (int ct = 0; ct < 4; ++ct) {
            acc[ct] = (f32x4){b0c[ct], b0c[ct], b0c[ct], b0c[ct]};
            acc[ct] = MFMA(bS0, w0h[0][ct], acc[ct]);
            acc[ct] = MFMA(bS1, w0h[1][ct], acc[ct]);
        }
        float xa[4][4], p[4];
#pragma unroll
        for (int j = 0; j < 4; ++j) {
#pragma unroll
            for (int ct = 0; ct < 4; ++ct)
                xa[ct][j] = fast_tanh(acc[ct][j]);
            p[j] = xa[0][j] * W1oc[0];
            p[j] = fmaf(xa[1][j], W1oc[1], p[j]);
            p[j] = fmaf(xa[2][j], W1oc[2], p[j]);
            p[j] = fmaf(xa[3][j], W1oc[3], p[j]);
            p[j] += __shfl_xor(p[j], 1, 64);
            p[j] += __shfl_xor(p[j], 2, 64);
            p[j] += __shfl_xor(p[j], 4, 64);
            p[j] += __shfl_xor(p[j], 8, 64);
        }
#pragma unroll
        for (int j = 0; j < 4; ++j) {
            const float e = exp2f(lrelu(a_self[j] + p[j]) * LOG2E);
            s[j] += e;
#pragma unroll
            for (int ct = 0; ct < 4; ++ct)
                xsum[ct][j] = fmaf(e, xa[ct][j], xsum[ct][j]);
        }
    }

    // ---------------- merge wave1 partials into wave0, write x_sum ----------------
    if (w == 1) {
#pragma unroll
        for (int j = 0; j < 4; ++j) {
#pragma unroll
            for (int ct = 0; ct < 4; ++ct)
                part[(lg * 4 + j) * 68 + ct * 16 + lr] = xsum[ct][j];
            if (lr == 0) ps[lg * 4 + j] = s[j];
        }
    }
    __syncthreads();
    if (w == 0) {
#pragma unroll
        for (int j = 0; j < 4; ++j) {
            const float stot = s[j] + ps[lg * 4 + j];
            const float inv = __fdividef(1.f, stot);
#pragma unroll
            for (int ct = 0; ct < 4; ++ct)
                xcat[(lg * 4 + j) * 132 + 64 + ct * 16 + lr] =
                    (xsum[ct][j] + part[(lg * 4 + j) * 68 + ct * 16 + lr]) * inv;
        }
    }
    __syncthreads();

    // ---------------- phase B (unchanged r12): wave w owns cols [w*64, w*64+64) ----------------
    float b2c[4], b3c[4], Wcc[4];
#pragma unroll
    for (int ct = 0; ct < 4; ++ct) {
        const int ctg = w * 4 + ct;
        b2c[ct] = b2[ctg * 16 + lr];
        b3c[ct] = b3[ctg * 16 + lr];
        Wcc[ct] = Wc[ctg * 16 + lr];
    }
    const float bcs = bcv[0];

    f32x4 acc2[4];
#pragma unroll
    for (int ct = 0; ct < 4; ++ct)
        acc2[ct] = (f32x4){b2c[ct], b2c[ct], b2c[ct], b2c[ct]};
#pragma unroll
    for (int ks = 0; ks < 4; ++ks) {
        const float* xr = xcat + lr * 132 + ks * 32 + lg * 8;
        float4 r0 = *reinterpret_cast<const float4*>(xr);
        float4 r1 = *reinterpret_cast<const float4*>(xr + 4);
        float av[8] = {r0.x, r0.y, r0.z, r0.w, r1.x, r1.y, r1.z, r1.w};
        f16x8 ah, al;
        split8(av, ah, al);
#pragma unroll
        for (int ct = 0; ct < 4; ++ct) {
            const int ctg = w * 4 + ct;
            const long gg = ((long)(ks * 8 + ctg) * 4 + lg) * 16 + lr;
            f16x8 bh = *reinterpret_cast<const f16x8*>(ws + 8192 + gg * 8);
            f16x8 bl = *reinterpret_cast<const f16x8*>(ws + 24576 + gg * 8);
            acc2[ct] = MFMA(al, bh, acc2[ct]);
            acc2[ct] = MFMA(ah, bl, acc2[ct]);
            acc2[ct] = MFMA(ah, bh, acc2[ct]);
        }
    }
    __syncthreads();   // all x_cat reads done before x1 overwrite
#pragma unroll
    for (int ct = 0; ct < 4; ++ct)
#pragma unroll
        for (int j = 0; j < 4; ++j)
            xcat[(lg * 4 + j) * 132 + (w * 4 + ct) * 16 + lr] = lrelu(acc2[ct][j]);
    __syncthreads();

#pragma unroll
    for (int ct = 0; ct < 4; ++ct)
        acc2[ct] = (f32x4){b3c[ct], b3c[ct], b3c[ct], b3c[ct]};
#pragma unroll
    for (int ks = 0; ks < 4; ++ks) {
        const float* xr = xcat + lr * 132 + ks * 32 + lg * 8;
        float4 r0 = *reinterpret_cast<const float4*>(xr);
        float4 r1 = *reinterpret_cast<const float4*>(xr + 4);
        float av[8] = {r0.x, r0.y, r0.z, r0.w, r1.x, r1.y, r1.z, r1.w};
        f16x8 ah, al;
        split8(av, ah, al);
#pragma unroll
        for (int ct = 0; ct < 4; ++ct) {
            const int ctg = w * 4 + ct;
            const long gg = ((long)(ks * 8 + ctg) * 4 + lg) * 16 + lr;
            f16x8 bh = *reinterpret_cast<const f16x8*>(ws + 40960 + gg * 8);
            f16x8 bl = *reinterpret_cast<const f16x8*>(ws + 57344 + gg * 8);
            acc2[ct] = MFMA(al, bh, acc2[ct]);
            acc2[ct] = MFMA(ah, bl, acc2[ct]);
            acc2[ct] = MFMA(ah, bh, acc2[ct]);
        }
    }

    // value: per-lane partials over this wave's 64 cols, butterfly over lr
    float v[4];
#pragma unroll
    for (int j = 0; j < 4; ++j) {
        v[j] = lrelu(acc2[0][j]) * Wcc[0];
#pragma unroll
        for (int ct = 1; ct < 4; ++ct)
            v[j] = fmaf(lrelu(acc2[ct][j]), Wcc[ct], v[j]);
        v[j] += __shfl_xor(v[j], 1, 64);
        v[j] += __shfl_xor(v[j], 2, 64);
        v[j] += __shfl_xor(v[j], 4, 64);
        v[j] += __shfl_xor(v[j], 8, 64);
    }
    if (lr == 0) {
#pragma unroll
        for (int j = 0; j < 4; ++j)
            vpart[w * 16 + lg * 4 + j] = v[j];
    }
    __syncthreads();
    if (w == 0 && lr == 0) {
#pragma unroll
        for (int j = 0; j < 4; ++j) {
            const int row = lg * 4 + j;
            out[ibase + row] = vpart[row] + vpart[16 + row] + bcs;
        }
    }
}

extern "C" void kernel_launch(void* const* d_in, const int* in_sizes, int n_in,
                              void* d_out, int out_size, void* d_ws, size_t ws_size,
                              hipStream_t stream) {
    (void)in_sizes; (void)n_in; (void)ws_size; (void)out_size;
    const float* obs = (const float*)d_in[0];
    const float* act = (const float*)d_in[1];
    const float* W0  = (const float*)d_in[2];
    const float* b0  = (const float*)d_in[3];
    const float* W1  = (const float*)d_in[4];
    const float* b1  = (const float*)d_in[5];
    const float* W2  = (const float*)d_in[6];
    const float* b2  = (const float*)d_in[7];
    const float* W3  = (const float*)d_in[8];
    const float* b3  = (const float*)d_in[9];
    const float* Wc  = (const float*)d_in[10];
    const float* bc  = (const float*)d_in[11];
    _Float16* ws = (_Float16*)d_ws;

    pack_weights<<<dim3(18), dim3(256), 0, stream>>>(W0, W2, W3, ws);
    critic_attention_kernel<<<dim3(65536 / 16), dim3(128), 0, stream>>>(
        obs, act, b0, W1, b1, b2, b3, Wc, bc, ws, (float*)d_out);
}

// Round 16
// 91.750 us; speedup vs baseline: 1.2884x; 1.0954x over previous
//
#include <hip/hip_runtime.h>
#include <math.h>

// critic_attention, round 16: r12 skeleton +
//  (1) obs staged via global_load_lds (block-major 2x1KB chunks/agent, 2-slot
//      ring, refill 2 iters ahead, counted vmcnt(4)) - prefetch depth moved
//      from VGPRs (r14's spill) to LDS.
//  (2) W0 hi-fp16 only (r15-validated: absmax unchanged) -> 8 MFMA/agent.
//  (3) x_cat stored fp16 in LDS -> phase B A-operand read directly as f16x8
//      (no split8: ~400 VALU cyc/wave saved, MFMA 96->64).
// vmcnt(4) proof: per iter exactly {2 gll + 2 act-loads} issued after the
// wait; slot(a)'s glls are >=5 ops old at wait(a) -> retired. Tail iters
// issue fewer ops -> wait is trivially satisfied AND slot glls (issued 2
// iters back with <=4 newer ops) are drained by the same count.
//
// Fragment conventions (m89-verified, rounds 6-15):
//   A-frag: lane row (l&15)=item, k=(l>>4)*8+e ; B-frag: lane col, same k
//   D: lane col (l&15), row=(l>>4)*4+reg = item
// ws layout (halfs): W0h@0[2][4][4][16][8] W0l@4096(unused) |
//   W2h@8192[4][8][4][16][8] W2l@24576 | W3h@40960 W3l@57344.

#define SLOPE 0.01f
#define LOG2E 1.4426950408889634f

typedef _Float16 f16x8 __attribute__((ext_vector_type(8)));
typedef float f32x4 __attribute__((ext_vector_type(4)));

#define MFMA(a, b, c) __builtin_amdgcn_mfma_f32_16x16x32_f16((a), (b), (c), 0, 0, 0)

typedef const __attribute__((address_space(1))) void GPTR;
typedef __attribute__((address_space(3))) void LPTR;

__device__ __forceinline__ void gll16(const float* g, float* l) {
    __builtin_amdgcn_global_load_lds((GPTR*)g, (LPTR*)l, 16, 0, 0);
}

__device__ __forceinline__ float lrelu(float x) { return fmaxf(x, SLOPE * x); }

__device__ __forceinline__ float fast_tanh(float x) {
    float e = exp2f(x * (2.0f * LOG2E));
    float r = __fdividef(1.0f, e + 1.0f);
    return fmaf(-2.0f, r, 1.0f);
}

__device__ __forceinline__ f16x8 cvt8(const float f[8]) {
    f16x8 r;
#pragma unroll
    for (int e = 0; e < 8; ++e) r[e] = (_Float16)f[e];
    return r;
}

// ---------------- prep: split weights into per-lane fp16 hi/lo fragments ----------------
__global__ __launch_bounds__(256) void pack_weights(
    const float* __restrict__ W0, const float* __restrict__ W2,
    const float* __restrict__ W3, _Float16* __restrict__ ws)
{
    const int g = blockIdx.x * 256 + threadIdx.x;
    if (g >= 4608) return;

    const float* src;
    int ks, ct, lg, lr, ncol, kmax;
    long hoff, loff;
    if (g < 512) {                       // W0: [2][4][4][16]
        ks = g >> 8; ct = (g >> 6) & 3; lg = (g >> 4) & 3; lr = g & 15;
        src = W0; ncol = 64; kmax = 40;
        hoff = (long)g * 8;  loff = hoff + 4096;
    } else if (g < 2560) {               // W2: [4][8][4][16]
        int gg = g - 512;
        ks = gg >> 9; ct = (gg >> 6) & 7; lg = (gg >> 4) & 3; lr = gg & 15;
        src = W2; ncol = 128; kmax = 128;
        hoff = 8192 + (long)gg * 8; loff = hoff + 16384;
    } else {                             // W3: [4][8][4][16]
        int gg = g - 2560;
        ks = gg >> 9; ct = (gg >> 6) & 7; lg = (gg >> 4) & 3; lr = gg & 15;
        src = W3; ncol = 128; kmax = 128;
        hoff = 40960 + (long)gg * 8; loff = hoff + 16384;
    }

    f16x8 hi, lo;
#pragma unroll
    for (int e = 0; e < 8; ++e) {
        const int k = ks * 32 + lg * 8 + e;
        const float v = (k < kmax) ? src[(long)k * ncol + ct * 16 + lr] : 0.f;
        _Float16 h = (_Float16)v;
        hi[e] = h;
        lo[e] = (_Float16)(v - (float)h);
    }
    *reinterpret_cast<f16x8*>(ws + hoff) = hi;
    *reinterpret_cast<f16x8*>(ws + loff) = lo;
}

__global__ __launch_bounds__(128, 2) void critic_attention_kernel(
    const float* __restrict__ obs, const float* __restrict__ act,
    const float* __restrict__ b0, const float* __restrict__ W1,
    const float* __restrict__ b1v, const float* __restrict__ b2,
    const float* __restrict__ b3, const float* __restrict__ Wc,
    const float* __restrict__ bcv, const _Float16* __restrict__ ws,
    float* __restrict__ out)
{
    __shared__ __align__(16) _Float16 xcat[16 * 136]; // x_cat/x1 as fp16, 16B-aligned rows
    __shared__ float part[16 * 68];    // wave1 partial xsum (fp32)
    __shared__ float ps[16];           // wave1 partial s
    __shared__ float vpart[32];        // Wc partials per wave
    __shared__ __align__(16) float obuf[2][2][512];   // [wave][slot][2KB agent tile]

    const int t = threadIdx.x;
    const int lane = t & 63;
    const int w = t >> 6;              // wave 0/1
    const int lr = lane & 15;          // A-row (item) / D-col
    const int lg = lane >> 4;          // k-chunk / D-row-group

    const long ibase = (long)blockIdx.x * 16;

    // W0 HI fragments only (r15-validated numerics)
    f16x8 w0h[2][4];
#pragma unroll
    for (int ks = 0; ks < 2; ++ks)
#pragma unroll
        for (int ct = 0; ct < 4; ++ct) {
            const long o = (((long)(ks * 4 + ct) * 4 + lg) * 16 + lr) * 8;
            w0h[ks][ct] = *reinterpret_cast<const f16x8*>(ws + o);
        }

    float b0c[4], W1sc[4], W1oc[4];
#pragma unroll
    for (int ct = 0; ct < 4; ++ct) {
        b0c[ct]  = b0[ct * 16 + lr];
        W1sc[ct] = W1[ct * 16 + lr];
        W1oc[ct] = W1[64 + ct * 16 + lr];
    }
    const float b1s = b1v[0];

    const float* obase = obs + (ibase + lr) * 512 + lg * 8;   // item-row view (peel)
    const float* abase = act + (ibase + lr) * 128;            // lg==0 lanes
    // gll source view: lane = (block b' = lane>>4, item = lane&15)
    const float* gb = obs + (ibase + (lane & 15)) * 512 + (lane >> 4) * 4;

    const int abeg = w ? 8 : 1;
    const int aend = w ? 16 : 8;

    // prologue: stage first two loop agents into the ring
    gll16(gb + abeg * 32,            &obuf[w][abeg & 1][0]);
    gll16(gb + abeg * 32 + 16,       &obuf[w][abeg & 1][256]);
    gll16(gb + (abeg + 1) * 32,      &obuf[w][(abeg + 1) & 1][0]);
    gll16(gb + (abeg + 1) * 32 + 16, &obuf[w][(abeg + 1) & 1][256]);

    // ---------------- agent 0 (register path): both waves need a_self ----------------
    float a_self[4], s[4], xsum[4][4];
    float4 c0 = make_float4(0.f, 0.f, 0.f, 0.f), c1 = c0;
    {
        float4 q0 = *reinterpret_cast<const float4*>(obase);
        float4 q1 = *reinterpret_cast<const float4*>(obase + 4);
        if (lg == 0) {
            c0 = *reinterpret_cast<const float4*>(abase);
            c1 = *reinterpret_cast<const float4*>(abase + 4);
        }
        float f0[8] = {q0.x, q0.y, q0.z, q0.w, q1.x, q1.y, q1.z, q1.w};
        float f1[8] = {c0.x, c0.y, c0.z, c0.w, c1.x, c1.y, c1.z, c1.w};
        f16x8 bi0 = cvt8(f0);
        f16x8 bi1 = cvt8(f1);

        f32x4 acc[4];
#pragma unroll
        for (int ct = 0; ct < 4; ++ct) {
            acc[ct] = (f32x4){b0c[ct], b0c[ct], b0c[ct], b0c[ct]};
            acc[ct] = MFMA(bi0, w0h[0][ct], acc[ct]);
            acc[ct] = MFMA(bi1, w0h[1][ct], acc[ct]);
        }

        float xa[4][4], p[4];
#pragma unroll
        for (int j = 0; j < 4; ++j) {
#pragma unroll
            for (int ct = 0; ct < 4; ++ct)
                xa[ct][j] = lrelu(acc[ct][j]);
            p[j] = xa[0][j] * W1sc[0];
            p[j] = fmaf(xa[1][j], W1sc[1], p[j]);
            p[j] = fmaf(xa[2][j], W1sc[2], p[j]);
            p[j] = fmaf(xa[3][j], W1sc[3], p[j]);
            p[j] += __shfl_xor(p[j], 1, 64);
            p[j] += __shfl_xor(p[j], 2, 64);
            p[j] += __shfl_xor(p[j], 4, 64);
            p[j] += __shfl_xor(p[j], 8, 64);
            a_self[j] = b1s + p[j];
            s[j] = 0.f;
#pragma unroll
            for (int ct = 0; ct < 4; ++ct) xsum[ct][j] = 0.f;
        }
        if (w == 0) {
#pragma unroll
            for (int ct = 0; ct < 4; ++ct)
#pragma unroll
                for (int j = 0; j < 4; ++j)
                    xcat[(lg * 4 + j) * 136 + ct * 16 + lr] = (_Float16)xa[ct][j];
        }
        // act for the first loop agent
        if (lg == 0) {
            c0 = *reinterpret_cast<const float4*>(abase + abeg * 8);
            c1 = *reinterpret_cast<const float4*>(abase + abeg * 8 + 4);
        }
    }

    // ---------------- "other" agents: LDS-staged obs, counted vmcnt ----------------
    for (int a = abeg; a < aend; ++a) {
        float* ob = &obuf[w][a & 1][0];
        asm volatile("s_waitcnt vmcnt(4)" ::: "memory");   // slot(a) glls complete
        float4 r0 = *reinterpret_cast<const float4*>(ob + 128 * lg + 4 * lr);
        float4 r1 = *reinterpret_cast<const float4*>(ob + 128 * lg + 64 + 4 * lr);
        float f0[8] = {r0.x, r0.y, r0.z, r0.w, r1.x, r1.y, r1.z, r1.w};
        float f1[8] = {c0.x, c0.y, c0.z, c0.w, c1.x, c1.y, c1.z, c1.w};
        f16x8 bi0 = cvt8(f0);   // cvt forces lgkm wait -> slot free before refill
        f16x8 bi1 = cvt8(f1);

        if (a + 2 < aend) {    // refill same slot for agent a+2 (~2 bodies of cover)
            gll16(gb + (a + 2) * 32,      ob);
            gll16(gb + (a + 2) * 32 + 16, ob + 256);
        }
        if (a + 1 < aend && lg == 0) {
            c0 = *reinterpret_cast<const float4*>(abase + (a + 1) * 8);
            c1 = *reinterpret_cast<const float4*>(abase + (a + 1) * 8 + 4);
        }

        f32x4 acc[4];
#pragma unroll
        for (int ct = 0; ct < 4; ++ct) {
            acc[ct] = (f32x4){b0c[ct], b0c[ct], b0c[ct], b0c[ct]};
            acc[ct] = MFMA(bi0, w0h[0][ct], acc[ct]);
            acc[ct] = MFMA(bi1, w0h[1][ct], acc[ct]);
        }

        float xa[4][4], p[4];
#pragma unroll
        for (int j = 0; j < 4; ++j) {
#pragma unroll
            for (int ct = 0; ct < 4; ++ct)
                xa[ct][j] = fast_tanh(acc[ct][j]);
            p[j] = xa[0][j] * W1oc[0];
            p[j] = fmaf(xa[1][j], W1oc[1], p[j]);
            p[j] = fmaf(xa[2][j], W1oc[2], p[j]);
            p[j] = fmaf(xa[3][j], W1oc[3], p[j]);
            p[j] += __shfl_xor(p[j], 1, 64);
            p[j] += __shfl_xor(p[j], 2, 64);
            p[j] += __shfl_xor(p[j], 4, 64);
            p[j] += __shfl_xor(p[j], 8, 64);
        }
#pragma unroll
        for (int j = 0; j < 4; ++j) {
            const float e = exp2f(lrelu(a_self[j] + p[j]) * LOG2E);
            s[j] += e;
#pragma unroll
            for (int ct = 0; ct < 4; ++ct)
                xsum[ct][j] = fmaf(e, xa[ct][j], xsum[ct][j]);
        }
    }

    // ---------------- merge wave1 partials into wave0, write x_sum (fp16) ----------------
    if (w == 1) {
#pragma unroll
        for (int j = 0; j < 4; ++j) {
#pragma unroll
            for (int ct = 0; ct < 4; ++ct)
                part[(lg * 4 + j) * 68 + ct * 16 + lr] = xsum[ct][j];
            if (lr == 0) ps[lg * 4 + j] = s[j];
        }
    }
    __syncthreads();
    if (w == 0) {
#pragma unroll
        for (int j = 0; j < 4; ++j) {
            const float stot = s[j] + ps[lg * 4 + j];
            const float inv = __fdividef(1.f, stot);
#pragma unroll
            for (int ct = 0; ct < 4; ++ct)
                xcat[(lg * 4 + j) * 136 + 64 + ct * 16 + lr] = (_Float16)(
                    (xsum[ct][j] + part[(lg * 4 + j) * 68 + ct * 16 + lr]) * inv);
        }
    }
    __syncthreads();

    // ---------------- phase B: fp16 A-operand direct from LDS ----------------
    float b2c[4], b3c[4], Wcc[4];
#pragma unroll
    for (int ct = 0; ct < 4; ++ct) {
        const int ctg = w * 4 + ct;
        b2c[ct] = b2[ctg * 16 + lr];
        b3c[ct] = b3[ctg * 16 + lr];
        Wcc[ct] = Wc[ctg * 16 + lr];
    }
    const float bcs = bcv[0];

    f32x4 acc2[4];
#pragma unroll
    for (int ct = 0; ct < 4; ++ct)
        acc2[ct] = (f32x4){b2c[ct], b2c[ct], b2c[ct], b2c[ct]};
#pragma unroll
    for (int ks = 0; ks < 4; ++ks) {
        f16x8 ah = *reinterpret_cast<const f16x8*>(&xcat[lr * 136 + ks * 32 + lg * 8]);
#pragma unroll
        for (int ct = 0; ct < 4; ++ct) {
            const int ctg = w * 4 + ct;
            const long gg = ((long)(ks * 8 + ctg) * 4 + lg) * 16 + lr;
            f16x8 bh = *reinterpret_cast<const f16x8*>(ws + 8192 + gg * 8);
            f16x8 bl = *reinterpret_cast<const f16x8*>(ws + 24576 + gg * 8);
            acc2[ct] = MFMA(ah, bl, acc2[ct]);
            acc2[ct] = MFMA(ah, bh, acc2[ct]);
        }
    }
    __syncthreads();   // all x_cat reads done before x1 overwrite
#pragma unroll
    for (int ct = 0; ct < 4; ++ct)
#pragma unroll
        for (int j = 0; j < 4; ++j)
            xcat[(lg * 4 + j) * 136 + (w * 4 + ct) * 16 + lr] =
                (_Float16)lrelu(acc2[ct][j]);
    __syncthreads();

#pragma unroll
    for (int ct = 0; ct < 4; ++ct)
        acc2[ct] = (f32x4){b3c[ct], b3c[ct], b3c[ct], b3c[ct]};
#pragma unroll
    for (int ks = 0; ks < 4; ++ks) {
        f16x8 ah = *reinterpret_cast<const f16x8*>(&xcat[lr * 136 + ks * 32 + lg * 8]);
#pragma unroll
        for (int ct = 0; ct < 4; ++ct) {
            const int ctg = w * 4 + ct;
            const long gg = ((long)(ks * 8 + ctg) * 4 + lg) * 16 + lr;
            f16x8 bh = *reinterpret_cast<const f16x8*>(ws + 40960 + gg * 8);
            f16x8 bl = *reinterpret_cast<const f16x8*>(ws + 57344 + gg * 8);
            acc2[ct] = MFMA(ah, bl, acc2[ct]);
            acc2[ct] = MFMA(ah, bh, acc2[ct]);
        }
    }

    // value: per-lane partials over this wave's 64 cols, butterfly over lr
    float v[4];
#pragma unroll
    for (int j = 0; j < 4; ++j) {
        v[j] = lrelu(acc2[0][j]) * Wcc[0];
#pragma unroll
        for (int ct = 1; ct < 4; ++ct)
            v[j] = fmaf(lrelu(acc2[ct][j]), Wcc[ct], v[j]);
        v[j] += __shfl_xor(v[j], 1, 64);
        v[j] += __shfl_xor(v[j], 2, 64);
        v[j] += __shfl_xor(v[j], 4, 64);
        v[j] += __shfl_xor(v[j], 8, 64);
    }
    if (lr == 0) {
#pragma unroll
        for (int j = 0; j < 4; ++j)
            vpart[w * 16 + lg * 4 + j] = v[j];
    }
    __syncthreads();
    if (w == 0 && lr == 0) {
#pragma unroll
        for (int j = 0; j < 4; ++j) {
            const int row = lg * 4 + j;
            out[ibase + row] = vpart[row] + vpart[16 + row] + bcs;
        }
    }
}

extern "C" void kernel_launch(void* const* d_in, const int* in_sizes, int n_in,
                              void* d_out, int out_size, void* d_ws, size_t ws_size,
                              hipStream_t stream) {
    (void)in_sizes; (void)n_in; (void)ws_size; (void)out_size;
    const float* obs = (const float*)d_in[0];
    const float* act = (const float*)d_in[1];
    const float* W0  = (const float*)d_in[2];
    const float* b0  = (const float*)d_in[3];
    const float* W1  = (const float*)d_in[4];
    const float* b1  = (const float*)d_in[5];
    const float* W2  = (const float*)d_in[6];
    const float* b2  = (const float*)d_in[7];
    const float* W3  = (const float*)d_in[8];
    const float* b3  = (const float*)d_in[9];
    const float* Wc  = (const float*)d_in[10];
    const float* bc  = (const float*)d_in[11];
    _Float16* ws = (_Float16*)d_ws;

    pack_weights<<<dim3(18), dim3(256), 0, stream>>>(W0, W2, W3, ws);
    critic_attention_kernel<<<dim3(65536 / 16), dim3(128), 0, stream>>>(
        obs, act, b0, W1, b1, b2, b3, Wc, bc, ws, (float*)d_out);
}

// Round 18
// 81.321 us; speedup vs baseline: 1.4536x; 1.1282x over previous
//
#include <hip/hip_runtime.h>
#include <math.h>

// critic_attention, round 18: r17 retry (compile fix: DPP ctrl must be a
// literal constant -> four explicit update_dpp calls, ctrl 0x121/2/4/8).
//  (1) ALL 16-lane reduces moved from __shfl_xor (ds_bpermute: LDS pipe,
//      ~40cyc/step, 4-deep serial, 130+/wave, bank-conflict traffic) to
//      DPP row_ror v_add all-reduce (VALU pipe, ~4cyc/step, no LDS).
//      Signature to verify: SQ_LDS_BANK_CONFLICT 524k -> ~0.
//  (2) W0 hi-fp16 only in phase A (r15-validated: absmax unchanged 4.88e-4)
//      -> 8 MFMA/agent (was 16), -16 VGPR (w0l gone) -> better residency.
// Everything else byte-identical to r12: 2-wave blocks on a 16-item tile,
// agent-split phase A, no-max softmax, LDS merge, col-split phase B with
// full hi/lo split-fp16 W2/W3, depth-1 register prefetch.
//
// Fragment conventions (m89-verified, rounds 6-16):
//   A-frag: lane row (l&15)=item, k=(l>>4)*8+e ; B-frag: lane col, same k
//   D: lane col (l&15), row=(l>>4)*4+reg = item
// ws layout (halfs): W0h@0[2][4][4][16][8] W0l@4096(unused) |
//   W2h@8192[4][8][4][16][8] W2l@24576 | W3h@40960 W3l@57344.

#define SLOPE 0.01f
#define LOG2E 1.4426950408889634f

typedef _Float16 f16x8 __attribute__((ext_vector_type(8)));
typedef float f32x4 __attribute__((ext_vector_type(4)));

#define MFMA(a, b, c) __builtin_amdgcn_mfma_f32_16x16x32_f16((a), (b), (c), 0, 0, 0)

__device__ __forceinline__ float lrelu(float x) { return fmaxf(x, SLOPE * x); }

__device__ __forceinline__ float fast_tanh(float x) {
    float e = exp2f(x * (2.0f * LOG2E));
    float r = __fdividef(1.0f, e + 1.0f);
    return fmaf(-2.0f, r, 1.0f);
}

__device__ __forceinline__ f16x8 cvt8(const float f[8]) {
    f16x8 r;
#pragma unroll
    for (int e = 0; e < 8; ++e) r[e] = (_Float16)f[e];
    return r;
}

__device__ __forceinline__ void split8(const float f[8], f16x8& hi, f16x8& lo) {
#pragma unroll
    for (int e = 0; e < 8; ++e) {
        _Float16 h = (_Float16)f[e];
        hi[e] = h;
        lo[e] = (_Float16)(f[e] - (float)h);
    }
}

// all-lanes sum within each 16-lane row: 4x v_add with DPP row_ror (VALU pipe,
// no ds_bpermute). ctrl literals: row_ror:1=0x121, :2=0x122, :4=0x124, :8=0x128.
__device__ __forceinline__ float dpp_add(float x, float acc_unused) { return x; }

__device__ __forceinline__ float rowsum16(float x) {
    int t;
    t = __builtin_amdgcn_update_dpp(0, __builtin_bit_cast(int, x), 0x121, 0xf, 0xf, true);
    x += __builtin_bit_cast(float, t);
    t = __builtin_amdgcn_update_dpp(0, __builtin_bit_cast(int, x), 0x122, 0xf, 0xf, true);
    x += __builtin_bit_cast(float, t);
    t = __builtin_amdgcn_update_dpp(0, __builtin_bit_cast(int, x), 0x124, 0xf, 0xf, true);
    x += __builtin_bit_cast(float, t);
    t = __builtin_amdgcn_update_dpp(0, __builtin_bit_cast(int, x), 0x128, 0xf, 0xf, true);
    x += __builtin_bit_cast(float, t);
    return x;
}

// ---------------- prep: split weights into per-lane fp16 hi/lo fragments ----------------
__global__ __launch_bounds__(256) void pack_weights(
    const float* __restrict__ W0, const float* __restrict__ W2,
    const float* __restrict__ W3, _Float16* __restrict__ ws)
{
    const int g = blockIdx.x * 256 + threadIdx.x;
    if (g >= 4608) return;

    const float* src;
    int ks, ct, lg, lr, ncol, kmax;
    long hoff, loff;
    if (g < 512) {                       // W0: [2][4][4][16]
        ks = g >> 8; ct = (g >> 6) & 3; lg = (g >> 4) & 3; lr = g & 15;
        src = W0; ncol = 64; kmax = 40;
        hoff = (long)g * 8;  loff = hoff + 4096;
    } else if (g < 2560) {               // W2: [4][8][4][16]
        int gg = g - 512;
        ks = gg >> 9; ct = (gg >> 6) & 7; lg = (gg >> 4) & 3; lr = gg & 15;
        src = W2; ncol = 128; kmax = 128;
        hoff = 8192 + (long)gg * 8; loff = hoff + 16384;
    } else {                             // W3: [4][8][4][16]
        int gg = g - 2560;
        ks = gg >> 9; ct = (gg >> 6) & 7; lg = (gg >> 4) & 3; lr = gg & 15;
        src = W3; ncol = 128; kmax = 128;
        hoff = 40960 + (long)gg * 8; loff = hoff + 16384;
    }

    f16x8 hi, lo;
#pragma unroll
    for (int e = 0; e < 8; ++e) {
        const int k = ks * 32 + lg * 8 + e;
        const float v = (k < kmax) ? src[(long)k * ncol + ct * 16 + lr] : 0.f;
        _Float16 h = (_Float16)v;
        hi[e] = h;
        lo[e] = (_Float16)(v - (float)h);
    }
    *reinterpret_cast<f16x8*>(ws + hoff) = hi;
    *reinterpret_cast<f16x8*>(ws + loff) = lo;
}

__global__ __launch_bounds__(128, 2) void critic_attention_kernel(
    const float* __restrict__ obs, const float* __restrict__ act,
    const float* __restrict__ b0, const float* __restrict__ W1,
    const float* __restrict__ b1v, const float* __restrict__ b2,
    const float* __restrict__ b3, const float* __restrict__ Wc,
    const float* __restrict__ bcv, const _Float16* __restrict__ ws,
    float* __restrict__ out)
{
    __shared__ float xcat[16 * 132];   // x_cat / x1, 16 items; stride 132 = 16B-aligned
    __shared__ float part[16 * 68];    // wave1 partial xsum
    __shared__ float ps[16];           // wave1 partial s
    __shared__ float vpart[32];        // Wc partials per wave

    const int t = threadIdx.x;
    const int lane = t & 63;
    const int w = t >> 6;              // wave 0/1
    const int lr = lane & 15;          // A-row (item) / D-col
    const int lg = lane >> 4;          // k-chunk / D-row-group

    const long ibase = (long)blockIdx.x * 16;

    // W0 HI fragments only (phase-A weights single-fp16; r15-validated)
    f16x8 w0h[2][4];
#pragma unroll
    for (int ks = 0; ks < 2; ++ks)
#pragma unroll
        for (int ct = 0; ct < 4; ++ct) {
            const long o = (((long)(ks * 4 + ct) * 4 + lg) * 16 + lr) * 8;
            w0h[ks][ct] = *reinterpret_cast<const f16x8*>(ws + o);
        }

    float b0c[4], W1sc[4], W1oc[4];
#pragma unroll
    for (int ct = 0; ct < 4; ++ct) {
        b0c[ct]  = b0[ct * 16 + lr];
        W1sc[ct] = W1[ct * 16 + lr];
        W1oc[ct] = W1[64 + ct * 16 + lr];
    }
    const float b1s = b1v[0];

    const float* obase = obs + (ibase + lr) * 512 + lg * 8;   // this lane's item row
    const float* abase = act + (ibase + lr) * 128;            // lg==0 lanes only

    const int abeg = w ? 8 : 1;        // wave0: agents 1..7; wave1: agents 8..15
    const int aend = w ? 16 : 8;

    float4 q0 = *reinterpret_cast<const float4*>(obase);
    float4 q1 = *reinterpret_cast<const float4*>(obase + 4);
    float4 c0 = make_float4(0.f, 0.f, 0.f, 0.f), c1 = c0;
    if (lg == 0) {
        c0 = *reinterpret_cast<const float4*>(abase);
        c1 = *reinterpret_cast<const float4*>(abase + 4);
    }

    // ---------------- agent 0: both waves (wave1 only needs a_self) ----------------
    float a_self[4], s[4], xsum[4][4];
    {
        float f0[8] = {q0.x, q0.y, q0.z, q0.w, q1.x, q1.y, q1.z, q1.w};
        float f1[8] = {c0.x, c0.y, c0.z, c0.w, c1.x, c1.y, c1.z, c1.w};
        f16x8 bi0 = cvt8(f0);
        f16x8 bi1 = cvt8(f1);

        // prefetch this wave's first loop agent
        q0 = *reinterpret_cast<const float4*>(obase + abeg * 32);
        q1 = *reinterpret_cast<const float4*>(obase + abeg * 32 + 4);
        if (lg == 0) {
            c0 = *reinterpret_cast<const float4*>(abase + abeg * 8);
            c1 = *reinterpret_cast<const float4*>(abase + abeg * 8 + 4);
        }

        f32x4 acc[4];
#pragma unroll
        for (int ct = 0; ct < 4; ++ct) {
            acc[ct] = (f32x4){b0c[ct], b0c[ct], b0c[ct], b0c[ct]};  // bias folded
            acc[ct] = MFMA(bi0, w0h[0][ct], acc[ct]);
            acc[ct] = MFMA(bi1, w0h[1][ct], acc[ct]);
        }

        float xa[4][4], p[4];
#pragma unroll
        for (int j = 0; j < 4; ++j) {
#pragma unroll
            for (int ct = 0; ct < 4; ++ct)
                xa[ct][j] = lrelu(acc[ct][j]);
            p[j] = xa[0][j] * W1sc[0];
            p[j] = fmaf(xa[1][j], W1sc[1], p[j]);
            p[j] = fmaf(xa[2][j], W1sc[2], p[j]);
            p[j] = fmaf(xa[3][j], W1sc[3], p[j]);
            p[j] = rowsum16(p[j]);                 // DPP all-reduce over lr
            a_self[j] = b1s + p[j];
            s[j] = 0.f;
#pragma unroll
            for (int ct = 0; ct < 4; ++ct) xsum[ct][j] = 0.f;
        }
        if (w == 0) {
#pragma unroll
            for (int ct = 0; ct < 4; ++ct)
#pragma unroll
                for (int j = 0; j < 4; ++j)
                    xcat[(lg * 4 + j) * 132 + ct * 16 + lr] = xa[ct][j];   // x_self
        }
    }

    // ---------------- this wave's 7-8 "other" agents: no-max softmax ----------------
    for (int a = abeg; a < aend; ++a) {
        float f0[8] = {q0.x, q0.y, q0.z, q0.w, q1.x, q1.y, q1.z, q1.w};
        float f1[8] = {c0.x, c0.y, c0.z, c0.w, c1.x, c1.y, c1.z, c1.w};
        f16x8 bi0 = cvt8(f0);
        f16x8 bi1 = cvt8(f1);

        if (a + 1 < aend) {   // prefetch next agent
            q0 = *reinterpret_cast<const float4*>(obase + (a + 1) * 32);
            q1 = *reinterpret_cast<const float4*>(obase + (a + 1) * 32 + 4);
            if (lg == 0) {
                c0 = *reinterpret_cast<const float4*>(abase + (a + 1) * 8);
                c1 = *reinterpret_cast<const float4*>(abase + (a + 1) * 8 + 4);
            }
        }

        f32x4 acc[4];
#pragma unroll
        for (int ct = 0; ct < 4; ++ct) {
            acc[ct] = (f32x4){b0c[ct], b0c[ct], b0c[ct], b0c[ct]};  // bias folded
            acc[ct] = MFMA(bi0, w0h[0][ct], acc[ct]);
            acc[ct] = MFMA(bi1, w0h[1][ct], acc[ct]);
        }

        float xa[4][4], p[4];
#pragma unroll
        for (int j = 0; j < 4; ++j) {
#pragma unroll
            for (int ct = 0; ct < 4; ++ct)
                xa[ct][j] = fast_tanh(acc[ct][j]);
            p[j] = xa[0][j] * W1oc[0];
            p[j] = fmaf(xa[1][j], W1oc[1], p[j]);
            p[j] = fmaf(xa[2][j], W1oc[2], p[j]);
            p[j] = fmaf(xa[3][j], W1oc[3], p[j]);
            p[j] = rowsum16(p[j]);                 // DPP all-reduce over lr
        }
        // bounded logits -> softmax without max-subtraction, pure accumulation
#pragma unroll
        for (int j = 0; j < 4; ++j) {
            const float e = exp2f(lrelu(a_self[j] + p[j]) * LOG2E);
            s[j] += e;
#pragma unroll
            for (int ct = 0; ct < 4; ++ct)
                xsum[ct][j] = fmaf(e, xa[ct][j], xsum[ct][j]);
        }
    }

    // ---------------- merge wave1 partials into wave0, write x_sum ----------------
    if (w == 1) {
#pragma unroll
        for (int j = 0; j < 4; ++j) {
#pragma unroll
            for (int ct = 0; ct < 4; ++ct)
                part[(lg * 4 + j) * 68 + ct * 16 + lr] = xsum[ct][j];
            if (lr == 0) ps[lg * 4 + j] = s[j];
        }
    }
    __syncthreads();
    if (w == 0) {
#pragma unroll
        for (int j = 0; j < 4; ++j) {
            const float stot = s[j] + ps[lg * 4 + j];
            const float inv = __fdividef(1.f, stot);
#pragma unroll
            for (int ct = 0; ct < 4; ++ct)
                xcat[(lg * 4 + j) * 132 + 64 + ct * 16 + lr] =
                    (xsum[ct][j] + part[(lg * 4 + j) * 68 + ct * 16 + lr]) * inv;
        }
    }
    __syncthreads();

    // ---------------- phase B: wave w owns cols [w*64, w*64+64) ----------------
    float b2c[4], b3c[4], Wcc[4];
#pragma unroll
    for (int ct = 0; ct < 4; ++ct) {
        const int ctg = w * 4 + ct;
        b2c[ct] = b2[ctg * 16 + lr];
        b3c[ct] = b3[ctg * 16 + lr];
        Wcc[ct] = Wc[ctg * 16 + lr];
    }
    const float bcs = bcv[0];

    f32x4 acc2[4];
#pragma unroll
    for (int ct = 0; ct < 4; ++ct)
        acc2[ct] = (f32x4){b2c[ct], b2c[ct], b2c[ct], b2c[ct]};   // bias folded
#pragma unroll
    for (int ks = 0; ks < 4; ++ks) {
        const float* xr = xcat + lr * 132 + ks * 32 + lg * 8;
        float4 r0 = *reinterpret_cast<const float4*>(xr);
        float4 r1 = *reinterpret_cast<const float4*>(xr + 4);
        float av[8] = {r0.x, r0.y, r0.z, r0.w, r1.x, r1.y, r1.z, r1.w};
        f16x8 ah, al;
        split8(av, ah, al);
#pragma unroll
        for (int ct = 0; ct < 4; ++ct) {
            const int ctg = w * 4 + ct;
            const long gg = ((long)(ks * 8 + ctg) * 4 + lg) * 16 + lr;
            f16x8 bh = *reinterpret_cast<const f16x8*>(ws + 8192 + gg * 8);
            f16x8 bl = *reinterpret_cast<const f16x8*>(ws + 24576 + gg * 8);
            acc2[ct] = MFMA(al, bh, acc2[ct]);
            acc2[ct] = MFMA(ah, bl, acc2[ct]);
            acc2[ct] = MFMA(ah, bh, acc2[ct]);
        }
    }
    __syncthreads();   // all x_cat reads done before x1 overwrite
#pragma unroll
    for (int ct = 0; ct < 4; ++ct)
#pragma unroll
        for (int j = 0; j < 4; ++j)
            xcat[(lg * 4 + j) * 132 + (w * 4 + ct) * 16 + lr] = lrelu(acc2[ct][j]);
    __syncthreads();

#pragma unroll
    for (int ct = 0; ct < 4; ++ct)
        acc2[ct] = (f32x4){b3c[ct], b3c[ct], b3c[ct], b3c[ct]};   // bias folded
#pragma unroll
    for (int ks = 0; ks < 4; ++ks) {
        const float* xr = xcat + lr * 132 + ks * 32 + lg * 8;
        float4 r0 = *reinterpret_cast<const float4*>(xr);
        float4 r1 = *reinterpret_cast<const float4*>(xr + 4);
        float av[8] = {r0.x, r0.y, r0.z, r0.w, r1.x, r1.y, r1.z, r1.w};
        f16x8 ah, al;
        split8(av, ah, al);
#pragma unroll
        for (int ct = 0; ct < 4; ++ct) {
            const int ctg = w * 4 + ct;
            const long gg = ((long)(ks * 8 + ctg) * 4 + lg) * 16 + lr;
            f16x8 bh = *reinterpret_cast<const f16x8*>(ws + 40960 + gg * 8);
            f16x8 bl = *reinterpret_cast<const f16x8*>(ws + 57344 + gg * 8);
            acc2[ct] = MFMA(al, bh, acc2[ct]);
            acc2[ct] = MFMA(ah, bl, acc2[ct]);
            acc2[ct] = MFMA(ah, bh, acc2[ct]);
        }
    }

    // value: per-lane partials over this wave's 64 cols, DPP all-reduce over lr
    float v[4];
#pragma unroll
    for (int j = 0; j < 4; ++j) {
        v[j] = lrelu(acc2[0][j]) * Wcc[0];
#pragma unroll
        for (int ct = 1; ct < 4; ++ct)
            v[j] = fmaf(lrelu(acc2[ct][j]), Wcc[ct], v[j]);
        v[j] = rowsum16(v[j]);
    }
    if (lr == 0) {
#pragma unroll
        for (int j = 0; j < 4; ++j)
            vpart[w * 16 + lg * 4 + j] = v[j];
    }
    __syncthreads();
    if (w == 0 && lr == 0) {
#pragma unroll
        for (int j = 0; j < 4; ++j) {
            const int row = lg * 4 + j;
            out[ibase + row] = vpart[row] + vpart[16 + row] + bcs;
        }
    }
}

extern "C" void kernel_launch(void* const* d_in, const int* in_sizes, int n_in,
                              void* d_out, int out_size, void* d_ws, size_t ws_size,
                              hipStream_t stream) {
    (void)in_sizes; (void)n_in; (void)ws_size; (void)out_size;
    const float* obs = (const float*)d_in[0];
    const float* act = (const float*)d_in[1];
    const float* W0  = (const float*)d_in[2];
    const float* b0  = (const float*)d_in[3];
    const float* W1  = (const float*)d_in[4];
    const float* b1  = (const float*)d_in[5];
    const float* W2  = (const float*)d_in[6];
    const float* b2  = (const float*)d_in[7];
    const float* W3  = (const float*)d_in[8];
    const float* b3  = (const float*)d_in[9];
    const float* Wc  = (const float*)d_in[10];
    const float* bc  = (const float*)d_in[11];
    _Float16* ws = (_Float16*)d_ws;

    pack_weights<<<dim3(18), dim3(256), 0, stream>>>(W0, W2, W3, ws);
    critic_attention_kernel<<<dim3(65536 / 16), dim3(128), 0, stream>>>(
        obs, act, b0, W1, b1, b2, b3, Wc, bc, ws, (float*)d_out);
}

// Round 20
// 60.992 us; speedup vs baseline: 1.9381x; 1.3333x over previous
//
#include <hip/hip_runtime.h>
#include <math.h>

// critic_attention, round 20: r19 retry (compile fix: cvt_pkrtz returns
// __fp16-vector, not _Float16-vector -> receive as h16x2 + bit_cast).
//  (1) raw HW transcendentals: __builtin_amdgcn_exp2f (v_exp_f32) and
//      __builtin_amdgcn_rcpf (v_rcp_f32, ~1ulp) replace exp2f/__fdividef
//      (no -ffast-math in harness -> those go through OCML wrapper ops).
//  (2) cvt8 via v_cvt_pkrtz_f16_f32: 8 scalar cvts -> 4 pack ops, output
//      already in MFMA packed-register layout.
//  (3) fp16 x_cat in LDS (r16-validated: absmax unchanged 4.88e-4): phase B
//      A-operand read directly as f16x8 -> no split8, MFMA 24->16/wave.
// Everything else identical to r18 champion (81.3us): 2-wave blocks,
// agent-split phase A with W0-hi-only MFMA (8/agent), DPP row_ror reduces,
// no-max softmax, LDS merge, col-split phase B with hi/lo split W2/W3.
//
// Fragment conventions (m89-verified, rounds 6-18):
//   A-frag: lane row (l&15)=item, k=(l>>4)*8+e ; B-frag: lane col, same k
//   D: lane col (l&15), row=(l>>4)*4+reg = item
// ws layout (halfs): W0h@0[2][4][4][16][8] W0l@4096(unused) |
//   W2h@8192[4][8][4][16][8] W2l@24576 | W3h@40960 W3l@57344.

#define SLOPE 0.01f
#define LOG2E 1.4426950408889634f

typedef _Float16 f16x8 __attribute__((ext_vector_type(8)));
typedef _Float16 f16x2 __attribute__((ext_vector_type(2)));
typedef __fp16 h16x2 __attribute__((ext_vector_type(2)));
typedef float f32x4 __attribute__((ext_vector_type(4)));

#define MFMA(a, b, c) __builtin_amdgcn_mfma_f32_16x16x32_f16((a), (b), (c), 0, 0, 0)

__device__ __forceinline__ float lrelu(float x) { return fmaxf(x, SLOPE * x); }

// tanh(x) = 1 - 2/(e^{2x}+1), raw v_exp_f32 + v_rcp_f32 (2 trans + 3 VALU)
__device__ __forceinline__ float fast_tanh(float x) {
    float e = __builtin_amdgcn_exp2f(x * (2.0f * LOG2E));
    float r = __builtin_amdgcn_rcpf(e + 1.0f);
    return fmaf(-2.0f, r, 1.0f);
}

// 8x f32 -> f16x8 via 4x v_cvt_pkrtz_f16_f32 (packed output = MFMA layout)
__device__ __forceinline__ f16x8 cvt8(const float f[8]) {
    f16x2 a = __builtin_bit_cast(f16x2, __builtin_amdgcn_cvt_pkrtz(f[0], f[1]));
    f16x2 b = __builtin_bit_cast(f16x2, __builtin_amdgcn_cvt_pkrtz(f[2], f[3]));
    f16x2 c = __builtin_bit_cast(f16x2, __builtin_amdgcn_cvt_pkrtz(f[4], f[5]));
    f16x2 d = __builtin_bit_cast(f16x2, __builtin_amdgcn_cvt_pkrtz(f[6], f[7]));
    f16x8 r;
    r[0] = a[0]; r[1] = a[1]; r[2] = b[0]; r[3] = b[1];
    r[4] = c[0]; r[5] = c[1]; r[6] = d[0]; r[7] = d[1];
    return r;
}

// all-lanes sum within each 16-lane row: 4x v_add with DPP row_ror (VALU pipe)
__device__ __forceinline__ float rowsum16(float x) {
    int t;
    t = __builtin_amdgcn_update_dpp(0, __builtin_bit_cast(int, x), 0x121, 0xf, 0xf, true);
    x += __builtin_bit_cast(float, t);
    t = __builtin_amdgcn_update_dpp(0, __builtin_bit_cast(int, x), 0x122, 0xf, 0xf, true);
    x += __builtin_bit_cast(float, t);
    t = __builtin_amdgcn_update_dpp(0, __builtin_bit_cast(int, x), 0x124, 0xf, 0xf, true);
    x += __builtin_bit_cast(float, t);
    t = __builtin_amdgcn_update_dpp(0, __builtin_bit_cast(int, x), 0x128, 0xf, 0xf, true);
    x += __builtin_bit_cast(float, t);
    return x;
}

// ---------------- prep: split weights into per-lane fp16 hi/lo fragments ----------------
__global__ __launch_bounds__(256) void pack_weights(
    const float* __restrict__ W0, const float* __restrict__ W2,
    const float* __restrict__ W3, _Float16* __restrict__ ws)
{
    const int g = blockIdx.x * 256 + threadIdx.x;
    if (g >= 4608) return;

    const float* src;
    int ks, ct, lg, lr, ncol, kmax;
    long hoff, loff;
    if (g < 512) {                       // W0: [2][4][4][16]
        ks = g >> 8; ct = (g >> 6) & 3; lg = (g >> 4) & 3; lr = g & 15;
        src = W0; ncol = 64; kmax = 40;
        hoff = (long)g * 8;  loff = hoff + 4096;
    } else if (g < 2560) {               // W2: [4][8][4][16]
        int gg = g - 512;
        ks = gg >> 9; ct = (gg >> 6) & 7; lg = (gg >> 4) & 3; lr = gg & 15;
        src = W2; ncol = 128; kmax = 128;
        hoff = 8192 + (long)gg * 8; loff = hoff + 16384;
    } else {                             // W3: [4][8][4][16]
        int gg = g - 2560;
        ks = gg >> 9; ct = (gg >> 6) & 7; lg = (gg >> 4) & 3; lr = gg & 15;
        src = W3; ncol = 128; kmax = 128;
        hoff = 40960 + (long)gg * 8; loff = hoff + 16384;
    }

    f16x8 hi, lo;
#pragma unroll
    for (int e = 0; e < 8; ++e) {
        const int k = ks * 32 + lg * 8 + e;
        const float v = (k < kmax) ? src[(long)k * ncol + ct * 16 + lr] : 0.f;
        _Float16 h = (_Float16)v;
        hi[e] = h;
        lo[e] = (_Float16)(v - (float)h);
    }
    *reinterpret_cast<f16x8*>(ws + hoff) = hi;
    *reinterpret_cast<f16x8*>(ws + loff) = lo;
}

__global__ __launch_bounds__(128, 2) void critic_attention_kernel(
    const float* __restrict__ obs, const float* __restrict__ act,
    const float* __restrict__ b0, const float* __restrict__ W1,
    const float* __restrict__ b1v, const float* __restrict__ b2,
    const float* __restrict__ b3, const float* __restrict__ Wc,
    const float* __restrict__ bcv, const _Float16* __restrict__ ws,
    float* __restrict__ out)
{
    __shared__ __align__(16) _Float16 xcat[16 * 136]; // x_cat/x1 fp16 (r16-validated)
    __shared__ float part[16 * 68];    // wave1 partial xsum (fp32)
    __shared__ float ps[16];           // wave1 partial s
    __shared__ float vpart[32];        // Wc partials per wave

    const int t = threadIdx.x;
    const int lane = t & 63;
    const int w = t >> 6;              // wave 0/1
    const int lr = lane & 15;          // A-row (item) / D-col
    const int lg = lane >> 4;          // k-chunk / D-row-group

    const long ibase = (long)blockIdx.x * 16;

    // W0 HI fragments only (phase-A weights single-fp16; r15-validated)
    f16x8 w0h[2][4];
#pragma unroll
    for (int ks = 0; ks < 2; ++ks)
#pragma unroll
        for (int ct = 0; ct < 4; ++ct) {
            const long o = (((long)(ks * 4 + ct) * 4 + lg) * 16 + lr) * 8;
            w0h[ks][ct] = *reinterpret_cast<const f16x8*>(ws + o);
        }

    float b0c[4], W1sc[4], W1oc[4];
#pragma unroll
    for (int ct = 0; ct < 4; ++ct) {
        b0c[ct]  = b0[ct * 16 + lr];
        W1sc[ct] = W1[ct * 16 + lr];
        W1oc[ct] = W1[64 + ct * 16 + lr];
    }
    const float b1s = b1v[0];

    const float* obase = obs + (ibase + lr) * 512 + lg * 8;   // this lane's item row
    const float* abase = act + (ibase + lr) * 128;            // lg==0 lanes only

    const int abeg = w ? 8 : 1;        // wave0: agents 1..7; wave1: agents 8..15
    const int aend = w ? 16 : 8;

    float4 q0 = *reinterpret_cast<const float4*>(obase);
    float4 q1 = *reinterpret_cast<const float4*>(obase + 4);
    float4 c0 = make_float4(0.f, 0.f, 0.f, 0.f), c1 = c0;
    if (lg == 0) {
        c0 = *reinterpret_cast<const float4*>(abase);
        c1 = *reinterpret_cast<const float4*>(abase + 4);
    }

    // ---------------- agent 0: both waves (wave1 only needs a_self) ----------------
    float a_self[4], s[4], xsum[4][4];
    {
        float f0[8] = {q0.x, q0.y, q0.z, q0.w, q1.x, q1.y, q1.z, q1.w};
        float f1[8] = {c0.x, c0.y, c0.z, c0.w, c1.x, c1.y, c1.z, c1.w};
        f16x8 bi0 = cvt8(f0);
        f16x8 bi1 = cvt8(f1);

        // prefetch this wave's first loop agent
        q0 = *reinterpret_cast<const float4*>(obase + abeg * 32);
        q1 = *reinterpret_cast<const float4*>(obase + abeg * 32 + 4);
        if (lg == 0) {
            c0 = *reinterpret_cast<const float4*>(abase + abeg * 8);
            c1 = *reinterpret_cast<const float4*>(abase + abeg * 8 + 4);
        }

        f32x4 acc[4];
#pragma unroll
        for (int ct = 0; ct < 4; ++ct) {
            acc[ct] = (f32x4){b0c[ct], b0c[ct], b0c[ct], b0c[ct]};  // bias folded
            acc[ct] = MFMA(bi0, w0h[0][ct], acc[ct]);
            acc[ct] = MFMA(bi1, w0h[1][ct], acc[ct]);
        }

        float xa[4][4], p[4];
#pragma unroll
        for (int j = 0; j < 4; ++j) {
#pragma unroll
            for (int ct = 0; ct < 4; ++ct)
                xa[ct][j] = lrelu(acc[ct][j]);
            p[j] = xa[0][j] * W1sc[0];
            p[j] = fmaf(xa[1][j], W1sc[1], p[j]);
            p[j] = fmaf(xa[2][j], W1sc[2], p[j]);
            p[j] = fmaf(xa[3][j], W1sc[3], p[j]);
            p[j] = rowsum16(p[j]);                 // DPP all-reduce over lr
            a_self[j] = b1s + p[j];
            s[j] = 0.f;
#pragma unroll
            for (int ct = 0; ct < 4; ++ct) xsum[ct][j] = 0.f;
        }
        if (w == 0) {
#pragma unroll
            for (int ct = 0; ct < 4; ++ct)
#pragma unroll
                for (int j = 0; j < 4; ++j)
                    xcat[(lg * 4 + j) * 136 + ct * 16 + lr] = (_Float16)xa[ct][j];
        }
    }

    // ---------------- this wave's 7-8 "other" agents: no-max softmax ----------------
    for (int a = abeg; a < aend; ++a) {
        float f0[8] = {q0.x, q0.y, q0.z, q0.w, q1.x, q1.y, q1.z, q1.w};
        float f1[8] = {c0.x, c0.y, c0.z, c0.w, c1.x, c1.y, c1.z, c1.w};
        f16x8 bi0 = cvt8(f0);
        f16x8 bi1 = cvt8(f1);

        if (a + 1 < aend) {   // prefetch next agent
            q0 = *reinterpret_cast<const float4*>(obase + (a + 1) * 32);
            q1 = *reinterpret_cast<const float4*>(obase + (a + 1) * 32 + 4);
            if (lg == 0) {
                c0 = *reinterpret_cast<const float4*>(abase + (a + 1) * 8);
                c1 = *reinterpret_cast<const float4*>(abase + (a + 1) * 8 + 4);
            }
        }

        f32x4 acc[4];
#pragma unroll
        for (int ct = 0; ct < 4; ++ct) {
            acc[ct] = (f32x4){b0c[ct], b0c[ct], b0c[ct], b0c[ct]};  // bias folded
            acc[ct] = MFMA(bi0, w0h[0][ct], acc[ct]);
            acc[ct] = MFMA(bi1, w0h[1][ct], acc[ct]);
        }

        float xa[4][4], p[4];
#pragma unroll
        for (int j = 0; j < 4; ++j) {
#pragma unroll
            for (int ct = 0; ct < 4; ++ct)
                xa[ct][j] = fast_tanh(acc[ct][j]);
            p[j] = xa[0][j] * W1oc[0];
            p[j] = fmaf(xa[1][j], W1oc[1], p[j]);
            p[j] = fmaf(xa[2][j], W1oc[2], p[j]);
            p[j] = fmaf(xa[3][j], W1oc[3], p[j]);
            p[j] = rowsum16(p[j]);                 // DPP all-reduce over lr
        }
        // bounded logits -> softmax without max-subtraction, pure accumulation
#pragma unroll
        for (int j = 0; j < 4; ++j) {
            const float e = __builtin_amdgcn_exp2f(lrelu(a_self[j] + p[j]) * LOG2E);
            s[j] += e;
#pragma unroll
            for (int ct = 0; ct < 4; ++ct)
                xsum[ct][j] = fmaf(e, xa[ct][j], xsum[ct][j]);
        }
    }

    // ---------------- merge wave1 partials into wave0, write x_sum (fp16) ----------------
    if (w == 1) {
#pragma unroll
        for (int j = 0; j < 4; ++j) {
#pragma unroll
            for (int ct = 0; ct < 4; ++ct)
                part[(lg * 4 + j) * 68 + ct * 16 + lr] = xsum[ct][j];
            if (lr == 0) ps[lg * 4 + j] = s[j];
        }
    }
    __syncthreads();
    if (w == 0) {
#pragma unroll
        for (int j = 0; j < 4; ++j) {
            const float stot = s[j] + ps[lg * 4 + j];
            const float inv = __builtin_amdgcn_rcpf(stot);
#pragma unroll
            for (int ct = 0; ct < 4; ++ct)
                xcat[(lg * 4 + j) * 136 + 64 + ct * 16 + lr] = (_Float16)(
                    (xsum[ct][j] + part[(lg * 4 + j) * 68 + ct * 16 + lr]) * inv);
        }
    }
    __syncthreads();

    // ---------------- phase B: fp16 A-operand direct from LDS ----------------
    float b2c[4], b3c[4], Wcc[4];
#pragma unroll
    for (int ct = 0; ct < 4; ++ct) {
        const int ctg = w * 4 + ct;
        b2c[ct] = b2[ctg * 16 + lr];
        b3c[ct] = b3[ctg * 16 + lr];
        Wcc[ct] = Wc[ctg * 16 + lr];
    }
    const float bcs = bcv[0];

    f32x4 acc2[4];
#pragma unroll
    for (int ct = 0; ct < 4; ++ct)
        acc2[ct] = (f32x4){b2c[ct], b2c[ct], b2c[ct], b2c[ct]};   // bias folded
#pragma unroll
    for (int ks = 0; ks < 4; ++ks) {
        f16x8 ah = *reinterpret_cast<const f16x8*>(&xcat[lr * 136 + ks * 32 + lg * 8]);
#pragma unroll
        for (int ct = 0; ct < 4; ++ct) {
            const int ctg = w * 4 + ct;
            const long gg = ((long)(ks * 8 + ctg) * 4 + lg) * 16 + lr;
            f16x8 bh = *reinterpret_cast<const f16x8*>(ws + 8192 + gg * 8);
            f16x8 bl = *reinterpret_cast<const f16x8*>(ws + 24576 + gg * 8);
            acc2[ct] = MFMA(ah, bl, acc2[ct]);
            acc2[ct] = MFMA(ah, bh, acc2[ct]);
        }
    }
    __syncthreads();   // all x_cat reads done before x1 overwrite
#pragma unroll
    for (int ct = 0; ct < 4; ++ct)
#pragma unroll
        for (int j = 0; j < 4; ++j)
            xcat[(lg * 4 + j) * 136 + (w * 4 + ct) * 16 + lr] =
                (_Float16)lrelu(acc2[ct][j]);
    __syncthreads();

#pragma unroll
    for (int ct = 0; ct < 4; ++ct)
        acc2[ct] = (f32x4){b3c[ct], b3c[ct], b3c[ct], b3c[ct]};   // bias folded
#pragma unroll
    for (int ks = 0; ks < 4; ++ks) {
        f16x8 ah = *reinterpret_cast<const f16x8*>(&xcat[lr * 136 + ks * 32 + lg * 8]);
#pragma unroll
        for (int ct = 0; ct < 4; ++ct) {
            const int ctg = w * 4 + ct;
            const long gg = ((long)(ks * 8 + ctg) * 4 + lg) * 16 + lr;
            f16x8 bh = *reinterpret_cast<const f16x8*>(ws + 40960 + gg * 8);
            f16x8 bl = *reinterpret_cast<const f16x8*>(ws + 57344 + gg * 8);
            acc2[ct] = MFMA(ah, bl, acc2[ct]);
            acc2[ct] = MFMA(ah, bh, acc2[ct]);
        }
    }

    // value: per-lane partials over this wave's 64 cols, DPP all-reduce over lr
    float v[4];
#pragma unroll
    for (int j = 0; j < 4; ++j) {
        v[j] = lrelu(acc2[0][j]) * Wcc[0];
#pragma unroll
        for (int ct = 1; ct < 4; ++ct)
            v[j] = fmaf(lrelu(acc2[ct][j]), Wcc[ct], v[j]);
        v[j] = rowsum16(v[j]);
    }
    if (lr == 0) {
#pragma unroll
        for (int j = 0; j < 4; ++j)
            vpart[w * 16 + lg * 4 + j] = v[j];
    }
    __syncthreads();
    if (w == 0 && lr == 0) {
#pragma unroll
        for (int j = 0; j < 4; ++j) {
            const int row = lg * 4 + j;
            out[ibase + row] = vpart[row] + vpart[16 + row] + bcs;
        }
    }
}

extern "C" void kernel_launch(void* const* d_in, const int* in_sizes, int n_in,
                              void* d_out, int out_size, void* d_ws, size_t ws_size,
                              hipStream_t stream) {
    (void)in_sizes; (void)n_in; (void)ws_size; (void)out_size;
    const float* obs = (const float*)d_in[0];
    const float* act = (const float*)d_in[1];
    const float* W0  = (const float*)d_in[2];
    const float* b0  = (const float*)d_in[3];
    const float* W1  = (const float*)d_in[4];
    const float* b1  = (const float*)d_in[5];
    const float* W2  = (const float*)d_in[6];
    const float* b2  = (const float*)d_in[7];
    const float* W3  = (const float*)d_in[8];
    const float* b3  = (const float*)d_in[9];
    const float* Wc  = (const float*)d_in[10];
    const float* bc  = (const float*)d_in[11];
    _Float16* ws = (_Float16*)d_ws;

    pack_weights<<<dim3(18), dim3(256), 0, stream>>>(W0, W2, W3, ws);
    critic_attention_kernel<<<dim3(65536 / 16), dim3(128), 0, stream>>>(
        obs, act, b0, W1, b1, b2, b3, Wc, bc, ws, (float*)d_out);
}